// Round 2
// baseline (7745.701 us; speedup 1.0000x reference)
//
#include <hip/hip_runtime.h>
#include <hip/hip_bf16.h>
#include <cstdint>
#include <cstddef>

#define DEVI __device__ __forceinline__

// ---------- constants ----------
#define BB 128
#define TT 30
#define VOCAB 10000
#define ENCD 2048
#define NPIX 49
#define GRID_P 256
#define FC_BLKS 157

typedef __attribute__((ext_vector_type(8))) short bf16x8;   // 8 bf16 in 4 VGPRs
typedef __attribute__((ext_vector_type(4))) float f32x4;

DEVI float bf2f(unsigned short u){ union{float f; unsigned int i;} x; x.i=((unsigned)u)<<16; return x.f; }
DEVI unsigned short f2bf(float f){ union{float f; unsigned int i;} x; x.f=f; unsigned r=x.i + 0x7fffu + ((x.i>>16)&1u); return (unsigned short)(r>>16); }
DEVI float sigm(float x){ return 1.0f/(1.0f+expf(-x)); }
DEVI f32x4 mfma16(bf16x8 a, bf16x8 b, f32x4 c){ return __builtin_amdgcn_mfma_f32_16x16x32_bf16(a,b,c,0,0,0); }

// ---------- grid barrier (device-scope, sense via generation counter) ----------
DEVI void gridbar(unsigned* cnt, unsigned* gen){
  __syncthreads();
  if(threadIdx.x==0){
    unsigned g = __hip_atomic_load(gen, __ATOMIC_RELAXED, __HIP_MEMORY_SCOPE_AGENT);
    unsigned v = __hip_atomic_fetch_add(cnt, 1u, __ATOMIC_RELEASE, __HIP_MEMORY_SCOPE_AGENT);
    if(v == GRID_P-1u){
      __hip_atomic_store(cnt, 0u, __ATOMIC_RELAXED, __HIP_MEMORY_SCOPE_AGENT);
      __hip_atomic_fetch_add(gen, 1u, __ATOMIC_ACQ_REL, __HIP_MEMORY_SCOPE_AGENT);
    } else {
      while(__hip_atomic_load(gen, __ATOMIC_RELAXED, __HIP_MEMORY_SCOPE_AGENT) == g)
        __builtin_amdgcn_s_sleep(1);
    }
    __builtin_amdgcn_fence(__ATOMIC_ACQUIRE, "agent");
  }
  __syncthreads();
}

// ---------- sort: stable descending by length ----------
__global__ void k_sort(const int* __restrict__ lens, int* __restrict__ order, int* __restrict__ Bt){
  __shared__ int L[BB];
  int i = threadIdx.x;
  L[i] = lens[i];
  __syncthreads();
  int li = L[i]; int rank = 0;
  for(int j=0;j<BB;j++){ int lj=L[j]; rank += (lj>li) || (lj==li && j<i); }
  order[rank] = i;
  if(i<TT){ int c=0; for(int j=0;j<BB;j++) c += (L[j]>i); Bt[i]=c; }
}

// ---------- weight f32 -> bf16 conversion ----------
struct WC13 { const float* src[13]; unsigned short* dst[13]; int n[13]; };
__global__ void k_wconv(WC13 wc){
  int stride = gridDim.x*blockDim.x;
  int tid0 = blockIdx.x*blockDim.x + threadIdx.x;
  for(int s=0;s<13;s++){
    const float4* src=(const float4*)wc.src[s];
    int n4 = wc.n[s]>>2;
    ushort4* dst=(ushort4*)wc.dst[s];
    for(int i=tid0;i<n4;i+=stride){
      float4 v=src[i];
      ushort4 o; o.x=f2bf(v.x); o.y=f2bf(v.y); o.z=f2bf(v.z); o.w=f2bf(v.w);
      dst[i]=o;
    }
  }
}

// ---------- xt build ----------
__global__ void k_xt(const int* __restrict__ caps, const int* __restrict__ order,
                     const float* __restrict__ embW, const unsigned short* __restrict__ gimg,
                     unsigned short* __restrict__ xt){
  int total=BB*TT*1024;
  for(int idx=blockIdx.x*blockDim.x+threadIdx.x; idx<total; idx+=gridDim.x*blockDim.x){
    int k=idx&1023; int bt=idx>>10; int t=bt%TT; int b=bt/TT;
    unsigned short v;
    if(k<512){ int tok=caps[order[b]*TT+t]; v=f2bf(embW[(size_t)tok*512+k]); }
    else v=gimg[b*512+(k-512)];
    xt[idx]=v;
  }
}

// ---------- GEMM, f32 A row-reordered -> bf16, 256-col tiles (low A re-fetch) ----------
__global__ __launch_bounds__(256) void k_gemm_f32A2(
    const float* __restrict__ A, int lda, int rpb, const int* __restrict__ order,
    const unsigned short* __restrict__ W, const float* __restrict__ bias,
    unsigned short* __restrict__ out, int K)
{
  __shared__ unsigned short As[128][136];
  int tid=threadIdx.x, wave=tid>>6, lane=tid&63, l15=lane&15, l4=lane>>4;
  int mb = blockIdx.y*128;
  f32x4 acc[8][4];
  f32x4 z = {0.f,0.f,0.f,0.f};
  #pragma unroll
  for(int i=0;i<8;i++)
    #pragma unroll
    for(int j=0;j<4;j++) acc[i][j]=z;
  int cch=tid&15, r0=tid>>4;
  int nb = blockIdx.x*256 + wave*64;
  for(int kc=0;kc<K;kc+=128){
    __syncthreads();
    #pragma unroll
    for(int rp=0;rp<8;rp++){
      int r=r0+rp*16;
      int m=mb+r;
      int sb = order[m/rpb]*rpb + m%rpb;
      const float* p = A + (size_t)sb*lda + kc + cch*8;
      float4 v0=*(const float4*)p, v1=*(const float4*)(p+4);
      unsigned short* d=&As[r][cch*8];
      d[0]=f2bf(v0.x); d[1]=f2bf(v0.y); d[2]=f2bf(v0.z); d[3]=f2bf(v0.w);
      d[4]=f2bf(v1.x); d[5]=f2bf(v1.y); d[6]=f2bf(v1.z); d[7]=f2bf(v1.w);
    }
    __syncthreads();
    #pragma unroll
    for(int kk=0;kk<4;kk++){
      bf16x8 bfr[4];
      #pragma unroll
      for(int nt=0;nt<4;nt++)
        bfr[nt] = *(const bf16x8*)(W + (size_t)(nb+nt*16+l15)*K + kc + kk*32 + l4*8);
      #pragma unroll
      for(int mt=0;mt<8;mt++){
        bf16x8 af = *(const bf16x8*)&As[mt*16+l15][kk*32+l4*8];
        #pragma unroll
        for(int nt=0;nt<4;nt++) acc[mt][nt]=mfma16(af,bfr[nt],acc[mt][nt]);
      }
    }
  }
  #pragma unroll
  for(int nt=0;nt<4;nt++){
    int n = nb + nt*16 + l15;
    float bs = bias[n];
    #pragma unroll
    for(int mt=0;mt<8;mt++){
      #pragma unroll
      for(int j=0;j<4;j++){
        int row = mb + mt*16 + l4*4 + j;
        float v = acc[mt][nt][j]+bs; v = v>0.f ? v : 0.f;
        out[(size_t)row*512 + n] = f2bf(v);
      }
    }
  }
}

// ---------- device GEMM: bf16 A (ld 512), bf16 W (512x512), one 64-col tile ----------
DEVI void dev_gemm512(unsigned short (*As)[136], const unsigned short* A, const unsigned short* W,
                      const float* bias, void* out, int act, int outbf, int xtile, int mb){
  int tid=threadIdx.x, wave=tid>>6, lane=tid&63, l15=lane&15, l4=lane>>4;
  f32x4 acc[8];
  f32x4 z = {0.f,0.f,0.f,0.f};
  #pragma unroll
  for(int i=0;i<8;i++) acc[i]=z;
  int cch=tid&15, r0=tid>>4;
  int nrow = xtile*64 + wave*16 + l15;
  for(int kc=0;kc<512;kc+=128){
    __syncthreads();
    #pragma unroll
    for(int rp=0;rp<8;rp++){
      int r=r0+rp*16;
      *(uint4*)&As[r][cch*8] = *(const uint4*)(A + (size_t)(mb+r)*512 + kc + cch*8);
    }
    __syncthreads();
    #pragma unroll
    for(int kk=0;kk<4;kk++){
      bf16x8 bfr = *(const bf16x8*)(W + (size_t)nrow*512 + kc + kk*32 + l4*8);
      #pragma unroll
      for(int mt=0;mt<8;mt++){
        bf16x8 af = *(const bf16x8*)&As[mt*16+l15][kk*32+l4*8];
        acc[mt]=mfma16(af,bfr,acc[mt]);
      }
    }
  }
  int n = xtile*64 + wave*16 + l15;
  float bs = bias ? bias[n] : 0.f;
  #pragma unroll
  for(int mt=0;mt<8;mt++){
    #pragma unroll
    for(int j=0;j<4;j++){
      int row = mb + mt*16 + l4*4 + j;
      float v = acc[mt][j]+bs;
      if(act==1) v = fmaxf(v,0.f);
      else if(act==2) v = tanhf(v);
      size_t idx=(size_t)row*512+n;
      if(outbf) ((unsigned short*)out)[idx]=f2bf(v);
      else ((float*)out)[idx]=v;
    }
  }
}

// global wrapper for precompute (vattn / SC)
struct GDesc { const unsigned short* A; const unsigned short* W; const float* bias; void* out; int act; int outbf; };
struct GDesc2 { GDesc d[2]; };
__global__ __launch_bounds__(256) void k_gemm512g(GDesc2 dd){
  __shared__ unsigned short As[128][136];
  GDesc g = dd.d[blockIdx.z];
  dev_gemm512(As, g.A, g.W, g.bias, g.out, g.act, g.outbf, blockIdx.x, blockIdx.y*128);
}

// ---------- persistent-kernel context ----------
struct PCtx {
  const unsigned short *xt, *w_ih, *w_hh, *w_xg, *w_hg;
  const unsigned short *w_saff, *w_satt, *w_haff, *w_hatt, *w_ctx, *w_fc;
  const unsigned short *vattn, *SC;
  const float *bih,*bhh,*bxg,*bhg, *sab,*stbias,*hab,*htb, *alW,*alb, *cxb, *fcb;
  const int *Bt;
  unsigned short *h0,*h1, *stb, *saff,*haff, *outl;
  float *c, *satt,*hatt,*scs,*sch;
  float *dout;
  unsigned *bar;   // [0]=cnt [1]=gen
};

// ---------- device LSTM tile (16 j-cols, 5 strips) ----------
DEVI void dev_lstm(unsigned short (*As)[136], const PCtx& p, int t, int jblk,
                   const unsigned short* hold, unsigned short* hnew){
  int tid=threadIdx.x, wave=tid>>6, lane=tid&63, l15=lane&15, l4=lane>>4;
  int jb = jblk*16;
  f32x4 acc[2][5];
  f32x4 z = {0.f,0.f,0.f,0.f};
  #pragma unroll
  for(int m=0;m<2;m++)
    #pragma unroll
    for(int s=0;s<5;s++) acc[m][s]=z;
  int cch=tid&15, r0=tid>>4;
  for(int kc=0;kc<1536;kc+=128){
    __syncthreads();
    #pragma unroll
    for(int rp=0;rp<8;rp++){
      int r=r0+rp*16;
      int kg = kc + cch*8;
      const unsigned short* src;
      if(kg<1024) src = p.xt + (size_t)r*(TT*1024) + t*1024 + kg;
      else        src = hold + (size_t)r*512 + (kg-1024);
      *(uint4*)&As[r][cch*8] = *(const uint4*)src;
    }
    __syncthreads();
    #pragma unroll
    for(int kk=0;kk<4;kk++){
      int kg = kc + kk*32 + l4*8;
      bf16x8 bfr[5];
      #pragma unroll
      for(int s=0;s<5;s++){
        int row = (s<4) ? (s*512 + jb + l15) : (jb + l15);
        const unsigned short* wp;
        if(s<4) wp = (kg<1024) ? (p.w_ih + (size_t)row*1024 + kg) : (p.w_hh + (size_t)row*512 + (kg-1024));
        else    wp = (kg<1024) ? (p.w_xg + (size_t)row*1024 + kg) : (p.w_hg + (size_t)row*512 + (kg-1024));
        bfr[s] = *(const bf16x8*)wp;
      }
      #pragma unroll
      for(int m=0;m<2;m++){
        int mt = wave*2+m;
        bf16x8 af = *(const bf16x8*)&As[mt*16+l15][kk*32+l4*8];
        #pragma unroll
        for(int s=0;s<5;s++) acc[m][s]=mfma16(af,bfr[s],acc[m][s]);
      }
    }
  }
  int bt = p.Bt[t];
  int j = jb + l15;
  float bi  = p.bih[j]      + p.bhh[j];
  float bff = p.bih[512+j]  + p.bhh[512+j];
  float bg  = p.bih[1024+j] + p.bhh[1024+j];
  float bo  = p.bih[1536+j] + p.bhh[1536+j];
  float bs  = p.bxg[j] + p.bhg[j];
  #pragma unroll
  for(int m=0;m<2;m++){
    int mt = wave*2+m;
    #pragma unroll
    for(int jj=0;jj<4;jj++){
      int b = mt*16 + l4*4 + jj;
      float iv = sigm(acc[m][0][jj]+bi);
      float fv = sigm(acc[m][1][jj]+bff);
      float gv = tanhf(acc[m][2][jj]+bg);
      float ov = sigm(acc[m][3][jj]+bo);
      float sv = sigm(acc[m][4][jj]+bs);
      float cold = (t==0) ? 0.f : p.c[(size_t)b*512+j];
      float cn = fv*cold + iv*gv;
      float tc = tanhf(cn);
      size_t idx=(size_t)b*512+j;
      if(b<bt){ hnew[idx]=f2bf(ov*tc); p.c[idx]=cn; }
      else    { hnew[idx]=hold[idx]; }
      p.stb[idx]=f2bf(sv*tc);
    }
  }
}

// ---------- device attention for one batch row ----------
DEVI void dev_attn(float* sS, float* sA, int b, const PCtx& p){
  int tid=threadIdx.x; int gid=tid>>4, gl=tid&15;
  const float* ha = p.hatt + (size_t)b*512;
  #pragma unroll
  for(int rp=0;rp<4;rp++){
    int pp = rp*16 + gid;
    float s = 0.f;
    if(pp<50){
      if(pp<NPIX){
        const unsigned short* vp = p.vattn + ((size_t)b*NPIX + pp)*512;
        for(int k=gl*32;k<gl*32+32;k++) s += tanhf(bf2f(vp[k]) + ha[k]) * p.alW[k];
      } else {
        const float* sa = p.satt + (size_t)b*512;
        for(int k=gl*32;k<gl*32+32;k++) s += tanhf(sa[k] + ha[k]) * p.alW[k];
      }
    }
    #pragma unroll
    for(int off=8;off>=1;off>>=1) s += __shfl_xor(s, off);
    if(gl==0 && pp<50) sS[pp] = s + p.alb[0];
  }
  __syncthreads();
  if(tid==0){
    float m=-1e30f;
    for(int pp=0;pp<50;pp++) m = fmaxf(m, sS[pp]);
    float sum=0.f;
    for(int pp=0;pp<50;pp++){ float e=expf(sS[pp]-m); sA[pp]=e; sum+=e; }
    float inv=1.f/sum;
    for(int pp=0;pp<50;pp++) sA[pp]*=inv;
  }
  __syncthreads();
  float a49 = sA[49];
  for(int n=tid;n<512;n+=256){
    float acc = p.sch[(size_t)b*512+n] + a49*p.scs[(size_t)b*512+n] + p.cxb[n];
    const unsigned short* sp = p.SC + (size_t)b*NPIX*512 + n;
    for(int pp=0;pp<NPIX;pp++) acc += sA[pp]*bf2f(sp[(size_t)pp*512]);
    p.outl[(size_t)b*512+n] = f2bf(tanhf(acc));
  }
  __syncthreads();
}

// ---------- device fc tile (64 vocab cols) ----------
DEVI void dev_fc(unsigned short (*As)[136], const PCtx& p, int t, int xtile){
  int tid=threadIdx.x, wave=tid>>6, lane=tid&63, l15=lane&15, l4=lane>>4;
  int bt = p.Bt[t];
  f32x4 acc[8];
  f32x4 z = {0.f,0.f,0.f,0.f};
  #pragma unroll
  for(int i=0;i<8;i++) acc[i]=z;
  int cch=tid&15, r0=tid>>4;
  int nbase = xtile*64 + wave*16;
  int nr = nbase + l15; if(nr > VOCAB-1) nr = VOCAB-1;
  for(int kc=0;kc<512;kc+=128){
    __syncthreads();
    #pragma unroll
    for(int rp=0;rp<8;rp++){
      int r=r0+rp*16;
      *(uint4*)&As[r][cch*8] = *(const uint4*)(p.outl + (size_t)r*512 + kc + cch*8);
    }
    __syncthreads();
    #pragma unroll
    for(int kk=0;kk<4;kk++){
      bf16x8 bfr = *(const bf16x8*)(p.w_fc + (size_t)nr*512 + kc + kk*32 + l4*8);
      #pragma unroll
      for(int mt=0;mt<8;mt++){
        if(mt*16 < bt){
          bf16x8 af = *(const bf16x8*)&As[mt*16+l15][kk*32+l4*8];
          acc[mt]=mfma16(af,bfr,acc[mt]);
        }
      }
    }
  }
  int n = nbase + l15; bool nok = n < VOCAB;
  float bs = nok ? p.fcb[n] : 0.f;
  #pragma unroll
  for(int mt=0;mt<8;mt++){
    #pragma unroll
    for(int j=0;j<4;j++){
      int b = mt*16 + l4*4 + j;
      float v = (b<bt) ? (acc[mt][j]+bs) : 0.f;
      if(nok) p.dout[(size_t)b*(TT*VOCAB) + (size_t)t*VOCAB + n] = v;
    }
  }
  __syncthreads();
}

// ---------- the persistent 30-step kernel ----------
__global__ __launch_bounds__(256) void k_persist(PCtx p){
  __shared__ unsigned short As[128][136];
  __shared__ float sS[52];
  __shared__ float sA[52];
  int cb = blockIdx.x;
  unsigned short* hold = p.h0;
  unsigned short* hnew = p.h1;
  unsigned* cnt = p.bar;
  unsigned* gen = p.bar+1;
  for(int t=0;t<=TT;t++){
    // P1: fc(t-1) overlapped with lstm(t)
    if(t>0 && cb<FC_BLKS) dev_fc(As, p, t-1, cb);
    if(t<TT && cb>=FC_BLKS && cb<FC_BLKS+32) dev_lstm(As, p, t, cb-FC_BLKS, hold, hnew);
    if(t==TT) break;
    gridbar(cnt,gen);
    // P2: saff (relu) / haff (tanh)
    if(cb<8)        dev_gemm512(As, p.stb, p.w_saff, p.sab, p.saff, 1, 1, cb,   0);
    else if(cb<16)  dev_gemm512(As, hnew,  p.w_haff, p.hab, p.haff, 2, 1, cb-8, 0);
    gridbar(cnt,gen);
    // P3: satt / hatt / scs / sch
    if(cb<8)        dev_gemm512(As, p.saff, p.w_satt, p.stbias, p.satt, 0, 0, cb,    0);
    else if(cb<16)  dev_gemm512(As, p.haff, p.w_hatt, p.htb,    p.hatt, 0, 0, cb-8,  0);
    else if(cb<24)  dev_gemm512(As, p.saff, p.w_ctx,  nullptr,  p.scs,  0, 0, cb-16, 0);
    else if(cb<32)  dev_gemm512(As, p.haff, p.w_ctx,  nullptr,  p.sch,  0, 0, cb-24, 0);
    gridbar(cnt,gen);
    // P4: attention + out_l
    if(cb<BB) dev_attn(sS, sA, cb, p);
    gridbar(cnt,gen);
    unsigned short* tmp=hold; hold=hnew; hnew=tmp;
  }
}

// ---------- host launch ----------
extern "C" void kernel_launch(void* const* d_in, const int* in_sizes, int n_in,
                              void* d_out, int out_size, void* d_ws, size_t ws_size,
                              hipStream_t stream)
{
  const float* enc  =(const float*)d_in[0];
  const float* gfeat=(const float*)d_in[1];
  const int*   caps =(const int*)d_in[2];
  const int*   lens =(const int*)d_in[3];
  const float* embW =(const float*)d_in[4];
  const float* e2hW =(const float*)d_in[5];  const float* e2hb=(const float*)d_in[6];
  const float* gfW  =(const float*)d_in[7];  const float* gfb =(const float*)d_in[8];
  const float* fcW  =(const float*)d_in[9];  const float* fcb =(const float*)d_in[10];
  const float* WihF =(const float*)d_in[11]; const float* bih =(const float*)d_in[12];
  const float* WhhF =(const float*)d_in[13]; const float* bhh =(const float*)d_in[14];
  const float* xgWF =(const float*)d_in[15]; const float* bxg =(const float*)d_in[16];
  const float* hgWF =(const float*)d_in[17]; const float* bhg =(const float*)d_in[18];
  const float* saWF =(const float*)d_in[19]; const float* sab =(const float*)d_in[20];
  const float* stWF =(const float*)d_in[21]; const float* stbias=(const float*)d_in[22];
  const float* haWF =(const float*)d_in[23]; const float* hab =(const float*)d_in[24];
  const float* htWF =(const float*)d_in[25]; const float* htb =(const float*)d_in[26];
  const float* vaWF =(const float*)d_in[27]; const float* vab =(const float*)d_in[28];
  const float* alW  =(const float*)d_in[29]; const float* alb =(const float*)d_in[30];
  const float* cxWF =(const float*)d_in[31]; const float* cxb =(const float*)d_in[32];

  char* base=(char*)d_ws; size_t off=0;
  auto alloc=[&](size_t bytes)->void*{ void* r=base+off; off += (bytes+255)&~(size_t)255; return r; };

  int* order=(int*)alloc(BB*4);
  int* Bt   =(int*)alloc(32*4);
  unsigned short* w_e2h =(unsigned short*)alloc((size_t)512*2048*2);
  unsigned short* w_gf  =(unsigned short*)alloc((size_t)512*2048*2);
  unsigned short* w_fc  =(unsigned short*)alloc((size_t)VOCAB*512*2);
  unsigned short* w_ih  =(unsigned short*)alloc((size_t)2048*1024*2);
  unsigned short* w_hh  =(unsigned short*)alloc((size_t)2048*512*2);
  unsigned short* w_xg  =(unsigned short*)alloc((size_t)512*1024*2);
  unsigned short* w_hg  =(unsigned short*)alloc((size_t)512*512*2);
  unsigned short* w_saff=(unsigned short*)alloc((size_t)512*512*2);
  unsigned short* w_satt=(unsigned short*)alloc((size_t)512*512*2);
  unsigned short* w_haff=(unsigned short*)alloc((size_t)512*512*2);
  unsigned short* w_hatt=(unsigned short*)alloc((size_t)512*512*2);
  unsigned short* w_vatt=(unsigned short*)alloc((size_t)512*512*2);
  unsigned short* w_ctx =(unsigned short*)alloc((size_t)512*512*2);
  unsigned short* spatial=(unsigned short*)alloc((size_t)BB*NPIX*512*2);
  unsigned short* vattn  =(unsigned short*)alloc((size_t)BB*NPIX*512*2);
  unsigned short* SC     =(unsigned short*)alloc((size_t)BB*NPIX*512*2);
  unsigned short* gimg   =(unsigned short*)alloc((size_t)BB*512*2);
  unsigned short* xt     =(unsigned short*)alloc((size_t)BB*TT*1024*2);
  unsigned short* hbuf0  =(unsigned short*)alloc((size_t)BB*512*2);
  unsigned short* hbuf1  =(unsigned short*)alloc((size_t)BB*512*2);
  float* cbuf =(float*)alloc((size_t)BB*512*4);
  unsigned short* stb_buf=(unsigned short*)alloc((size_t)BB*512*2);
  unsigned short* saff   =(unsigned short*)alloc((size_t)BB*512*2);
  unsigned short* haff   =(unsigned short*)alloc((size_t)BB*512*2);
  float* satt=(float*)alloc((size_t)BB*512*4);
  float* hatt=(float*)alloc((size_t)BB*512*4);
  float* scs =(float*)alloc((size_t)BB*512*4);
  float* sch =(float*)alloc((size_t)BB*512*4);
  unsigned short* outl=(unsigned short*)alloc((size_t)BB*512*2);
  unsigned* bar=(unsigned*)alloc(256);

  hipMemsetAsync(hbuf0, 0, (size_t)BB*512*2, stream);
  hipMemsetAsync(bar, 0, 8, stream);

  k_sort<<<1,BB,0,stream>>>(lens, order, Bt);

  WC13 wc;
  const float* srcs[13] = {e2hW,gfW,fcW,WihF,WhhF,xgWF,hgWF,saWF,stWF,haWF,htWF,vaWF,cxWF};
  unsigned short* dsts[13] = {w_e2h,w_gf,w_fc,w_ih,w_hh,w_xg,w_hg,w_saff,w_satt,w_haff,w_hatt,w_vatt,w_ctx};
  int ns[13] = {512*2048,512*2048,VOCAB*512,2048*1024,2048*512,512*1024,512*512,512*512,512*512,512*512,512*512,512*512,512*512};
  for(int i=0;i<13;i++){ wc.src[i]=srcs[i]; wc.dst[i]=dsts[i]; wc.n[i]=ns[i]; }
  k_wconv<<<1024,256,0,stream>>>(wc);

  // spatial = relu(enc[order] @ e2h^T + b), gimg = relu(gf[order] @ gf_W^T + b)
  k_gemm_f32A2<<<dim3(2,NPIX),256,0,stream>>>(enc, ENCD, NPIX, order, w_e2h, e2hb, spatial, ENCD);
  k_gemm_f32A2<<<dim3(2,1),  256,0,stream>>>(gfeat, ENCD, 1, order, w_gf, gfb, gimg, ENCD);
  k_xt<<<1024,256,0,stream>>>(caps, order, embW, gimg, xt);

  {
    GDesc2 dv{};
    dv.d[0] = GDesc{spatial, w_vatt, vab,     vattn, 0, 1};
    dv.d[1] = GDesc{spatial, w_ctx,  nullptr, SC,    0, 1};
    k_gemm512g<<<dim3(8,NPIX,2),256,0,stream>>>(dv);
  }

  PCtx pc;
  pc.xt=xt; pc.w_ih=w_ih; pc.w_hh=w_hh; pc.w_xg=w_xg; pc.w_hg=w_hg;
  pc.w_saff=w_saff; pc.w_satt=w_satt; pc.w_haff=w_haff; pc.w_hatt=w_hatt; pc.w_ctx=w_ctx; pc.w_fc=w_fc;
  pc.vattn=vattn; pc.SC=SC;
  pc.bih=bih; pc.bhh=bhh; pc.bxg=bxg; pc.bhg=bhg;
  pc.sab=sab; pc.stbias=stbias; pc.hab=hab; pc.htb=htb;
  pc.alW=alW; pc.alb=alb; pc.cxb=cxb; pc.fcb=fcb;
  pc.Bt=Bt;
  pc.h0=hbuf0; pc.h1=hbuf1; pc.stb=stb_buf; pc.saff=saff; pc.haff=haff; pc.outl=outl;
  pc.c=cbuf; pc.satt=satt; pc.hatt=hatt; pc.scs=scs; pc.sch=sch;
  pc.dout=(float*)d_out;
  pc.bar=bar;

  k_persist<<<GRID_P,256,0,stream>>>(pc);
}

// Round 3
// 2812.722 us; speedup vs baseline: 2.7538x; 2.7538x over previous
//
#include <hip/hip_runtime.h>
#include <hip/hip_bf16.h>
#include <cstdint>
#include <cstddef>

#define DEVI __device__ __forceinline__

// ---------- constants ----------
#define BB 128
#define TT 30
#define VOCAB 10000
#define ENCD 2048
#define NPIX 49
#define SLOT 65536   // 128*512 elements

typedef __attribute__((ext_vector_type(8))) short bf16x8;
typedef __attribute__((ext_vector_type(4))) float f32x4;

DEVI float bf2f(unsigned short u){ union{float f; unsigned int i;} x; x.i=((unsigned)u)<<16; return x.f; }
DEVI unsigned short f2bf(float f){ union{float f; unsigned int i;} x; x.f=f; unsigned r=x.i + 0x7fffu + ((x.i>>16)&1u); return (unsigned short)(r>>16); }
DEVI float sigm(float x){ return 1.0f/(1.0f+expf(-x)); }
DEVI f32x4 mfma16(bf16x8 a, bf16x8 b, f32x4 c){ return __builtin_amdgcn_mfma_f32_16x16x32_bf16(a,b,c,0,0,0); }

// ---------- flag-array sync: parallel release-stores + one vector poll ----------
DEVI void waitflags(int* flags, int thresh){
  __syncthreads();
  if(threadIdx.x < 64){
    for(;;){
      int v = (threadIdx.x<32) ? __hip_atomic_load(&flags[threadIdx.x], __ATOMIC_RELAXED, __HIP_MEMORY_SCOPE_AGENT)
                               : 0x7fffffff;
      if(__all(v >= thresh)) break;
      __builtin_amdgcn_s_sleep(1);
    }
    __builtin_amdgcn_fence(__ATOMIC_ACQUIRE, "agent");
  }
  __syncthreads();
}
DEVI void signal(int* flag, int val){
  __syncthreads();   // drains vmcnt: all block stores are in L2 before the release
  if(threadIdx.x==0) __hip_atomic_store(flag, val, __ATOMIC_RELEASE, __HIP_MEMORY_SCOPE_AGENT);
}

// ---------- sort: stable descending by length ----------
__global__ void k_sort(const int* __restrict__ lens, int* __restrict__ order, int* __restrict__ Bt){
  __shared__ int L[BB];
  int i = threadIdx.x;
  L[i] = lens[i];
  __syncthreads();
  int li = L[i]; int rank = 0;
  for(int j=0;j<BB;j++){ int lj=L[j]; rank += (lj>li) || (lj==li && j<i); }
  order[rank] = i;
  if(i<TT){ int c=0; for(int j=0;j<BB;j++) c += (L[j]>i); Bt[i]=c; }
}

// ---------- weight f32 -> bf16 conversion ----------
struct WC13 { const float* src[13]; unsigned short* dst[13]; int n[13]; };
__global__ void k_wconv(WC13 wc){
  int stride = gridDim.x*blockDim.x;
  int tid0 = blockIdx.x*blockDim.x + threadIdx.x;
  for(int s=0;s<13;s++){
    const float4* src=(const float4*)wc.src[s];
    int n4 = wc.n[s]>>2;
    ushort4* dst=(ushort4*)wc.dst[s];
    for(int i=tid0;i<n4;i+=stride){
      float4 v=src[i];
      ushort4 o; o.x=f2bf(v.x); o.y=f2bf(v.y); o.z=f2bf(v.z); o.w=f2bf(v.w);
      dst[i]=o;
    }
  }
}

// ---------- xt build ----------
__global__ void k_xt(const int* __restrict__ caps, const int* __restrict__ order,
                     const float* __restrict__ embW, const unsigned short* __restrict__ gimg,
                     unsigned short* __restrict__ xt){
  int total=BB*TT*1024;
  for(int idx=blockIdx.x*blockDim.x+threadIdx.x; idx<total; idx+=gridDim.x*blockDim.x){
    int k=idx&1023; int bt=idx>>10; int t=bt%TT; int b=bt/TT;
    unsigned short v;
    if(k<512){ int tok=caps[order[b]*TT+t]; v=f2bf(embW[(size_t)tok*512+k]); }
    else v=gimg[b*512+(k-512)];
    xt[idx]=v;
  }
}

// ---------- GEMM, f32 A row-reordered -> bf16, 256-col tiles ----------
__global__ __launch_bounds__(256) void k_gemm_f32A2(
    const float* __restrict__ A, int lda, int rpb, const int* __restrict__ order,
    const unsigned short* __restrict__ W, const float* __restrict__ bias,
    unsigned short* __restrict__ out, int K)
{
  __shared__ unsigned short As[128][136];
  int tid=threadIdx.x, wave=tid>>6, lane=tid&63, l15=lane&15, l4=lane>>4;
  int mb = blockIdx.y*128;
  f32x4 acc[8][4];
  f32x4 z = {0.f,0.f,0.f,0.f};
  #pragma unroll
  for(int i=0;i<8;i++)
    #pragma unroll
    for(int j=0;j<4;j++) acc[i][j]=z;
  int cch=tid&15, r0=tid>>4;
  int nb = blockIdx.x*256 + wave*64;
  for(int kc=0;kc<K;kc+=128){
    __syncthreads();
    #pragma unroll
    for(int rp=0;rp<8;rp++){
      int r=r0+rp*16;
      int m=mb+r;
      int sb = order[m/rpb]*rpb + m%rpb;
      const float* p = A + (size_t)sb*lda + kc + cch*8;
      float4 v0=*(const float4*)p, v1=*(const float4*)(p+4);
      unsigned short* d=&As[r][cch*8];
      d[0]=f2bf(v0.x); d[1]=f2bf(v0.y); d[2]=f2bf(v0.z); d[3]=f2bf(v0.w);
      d[4]=f2bf(v1.x); d[5]=f2bf(v1.y); d[6]=f2bf(v1.z); d[7]=f2bf(v1.w);
    }
    __syncthreads();
    #pragma unroll
    for(int kk=0;kk<4;kk++){
      bf16x8 bfr[4];
      #pragma unroll
      for(int nt=0;nt<4;nt++)
        bfr[nt] = *(const bf16x8*)(W + (size_t)(nb+nt*16+l15)*K + kc + kk*32 + l4*8);
      #pragma unroll
      for(int mt=0;mt<8;mt++){
        bf16x8 af = *(const bf16x8*)&As[mt*16+l15][kk*32+l4*8];
        #pragma unroll
        for(int nt=0;nt<4;nt++) acc[mt][nt]=mfma16(af,bfr[nt],acc[mt][nt]);
      }
    }
  }
  #pragma unroll
  for(int nt=0;nt<4;nt++){
    int n = nb + nt*16 + l15;
    float bs = bias[n];
    #pragma unroll
    for(int mt=0;mt<8;mt++){
      #pragma unroll
      for(int j=0;j<4;j++){
        int row = mb + mt*16 + l4*4 + j;
        float v = acc[mt][nt][j]+bs; v = v>0.f ? v : 0.f;
        out[(size_t)row*512 + n] = f2bf(v);
      }
    }
  }
}

// ---------- device GEMM: bf16 A (ld 512), bf16 W (512x512), one 64-col tile, bf16 out ----------
DEVI void dev_gemm512(unsigned short (*As)[136], const unsigned short* A, const unsigned short* W,
                      const float* bias, unsigned short* out, int act, int xtile, int mb){
  int tid=threadIdx.x, wave=tid>>6, lane=tid&63, l15=lane&15, l4=lane>>4;
  f32x4 acc[8];
  f32x4 z = {0.f,0.f,0.f,0.f};
  #pragma unroll
  for(int i=0;i<8;i++) acc[i]=z;
  int cch=tid&15, r0=tid>>4;
  int nrow = xtile*64 + wave*16 + l15;
  for(int kc=0;kc<512;kc+=128){
    __syncthreads();
    #pragma unroll
    for(int rp=0;rp<8;rp++){
      int r=r0+rp*16;
      *(uint4*)&As[r][cch*8] = *(const uint4*)(A + (size_t)(mb+r)*512 + kc + cch*8);
    }
    __syncthreads();
    #pragma unroll
    for(int kk=0;kk<4;kk++){
      bf16x8 bfr = *(const bf16x8*)(W + (size_t)nrow*512 + kc + kk*32 + l4*8);
      #pragma unroll
      for(int mt=0;mt<8;mt++){
        bf16x8 af = *(const bf16x8*)&As[mt*16+l15][kk*32+l4*8];
        acc[mt]=mfma16(af,bfr,acc[mt]);
      }
    }
  }
  float bs = bias ? bias[nrow] : 0.f;
  #pragma unroll
  for(int mt=0;mt<8;mt++){
    #pragma unroll
    for(int j=0;j<4;j++){
      int row = mb + mt*16 + l4*4 + j;
      float v = acc[mt][j]+bs;
      if(act==1) v = fmaxf(v,0.f);
      else if(act==2) v = tanhf(v);
      out[(size_t)row*512+nrow]=f2bf(v);
    }
  }
  __syncthreads();
}

// precompute wrapper (vattn / SC)
struct PreD { const unsigned short* A; const unsigned short* W; const float* bias; unsigned short* out; };
struct PreD2 { PreD d[2]; };
__global__ __launch_bounds__(256) void k_pre(PreD2 dd){
  __shared__ unsigned short As[128][136];
  PreD g = dd.d[blockIdx.z];
  dev_gemm512(As, g.A, g.W, g.bias, g.out, 0, blockIdx.x, blockIdx.y*128);
}

// ---------- persistent-kernel context ----------
struct PCtx {
  const unsigned short *xt, *w_ih, *w_hh, *w_xg, *w_hg;
  const unsigned short *w_saff, *w_satt, *w_haff, *w_hatt, *w_ctx, *w_fc;
  const unsigned short *vattn, *SC;
  const float *bih,*bhh,*bxg,*bhg, *sab,*stbias,*hab,*htb, *alW,*alb, *cxb, *fcb;
  const int *Bt;
  unsigned short *h_hist;   // (TT+1) slots of 128x512 bf16; slot 0 zeroed
  unsigned short *stb;      // TT slots
  unsigned short *tbuf;     // 7 teams x 7 bufs x SLOT
  float *dout;
  int *Lflag;               // [32]
  int *Tflag;               // [7*32]
};

// ---------- device LSTM tile (16 j-cols, 5 strips), c in registers ----------
DEVI void dev_lstm(unsigned short (*As)[136], const PCtx& p, int t, int jblk,
                   const unsigned short* hprev, unsigned short* hout, float creg[2][4]){
  int tid=threadIdx.x, wave=tid>>6, lane=tid&63, l15=lane&15, l4=lane>>4;
  int jb = jblk*16;
  f32x4 acc[2][5];
  f32x4 z = {0.f,0.f,0.f,0.f};
  #pragma unroll
  for(int m=0;m<2;m++)
    #pragma unroll
    for(int s=0;s<5;s++) acc[m][s]=z;
  int cch=tid&15, r0=tid>>4;
  for(int kc=0;kc<1536;kc+=128){
    __syncthreads();
    #pragma unroll
    for(int rp=0;rp<8;rp++){
      int r=r0+rp*16;
      int kg = kc + cch*8;
      const unsigned short* src;
      if(kg<1024) src = p.xt + (size_t)r*(TT*1024) + t*1024 + kg;
      else        src = hprev + (size_t)r*512 + (kg-1024);
      *(uint4*)&As[r][cch*8] = *(const uint4*)src;
    }
    __syncthreads();
    #pragma unroll
    for(int kk=0;kk<4;kk++){
      int kg = kc + kk*32 + l4*8;
      bf16x8 bfr[5];
      #pragma unroll
      for(int s=0;s<5;s++){
        int row = (s<4) ? (s*512 + jb + l15) : (jb + l15);
        const unsigned short* wp;
        if(s<4) wp = (kg<1024) ? (p.w_ih + (size_t)row*1024 + kg) : (p.w_hh + (size_t)row*512 + (kg-1024));
        else    wp = (kg<1024) ? (p.w_xg + (size_t)row*1024 + kg) : (p.w_hg + (size_t)row*512 + (kg-1024));
        bfr[s] = *(const bf16x8*)wp;
      }
      #pragma unroll
      for(int m=0;m<2;m++){
        int mt = wave*2+m;
        bf16x8 af = *(const bf16x8*)&As[mt*16+l15][kk*32+l4*8];
        #pragma unroll
        for(int s=0;s<5;s++) acc[m][s]=mfma16(af,bfr[s],acc[m][s]);
      }
    }
  }
  int bt = p.Bt[t];
  int j = jb + l15;
  float bi  = p.bih[j]      + p.bhh[j];
  float bff = p.bih[512+j]  + p.bhh[512+j];
  float bg  = p.bih[1024+j] + p.bhh[1024+j];
  float bo  = p.bih[1536+j] + p.bhh[1536+j];
  float bs  = p.bxg[j] + p.bhg[j];
  unsigned short* stt = p.stb + (size_t)t*SLOT;
  #pragma unroll
  for(int m=0;m<2;m++){
    int mt = wave*2+m;
    #pragma unroll
    for(int jj=0;jj<4;jj++){
      int b = mt*16 + l4*4 + jj;
      float iv = sigm(acc[m][0][jj]+bi);
      float fv = sigm(acc[m][1][jj]+bff);
      float gv = tanhf(acc[m][2][jj]+bg);
      float ov = sigm(acc[m][3][jj]+bo);
      float sv = sigm(acc[m][4][jj]+bs);
      float cn = fv*creg[m][jj] + iv*gv;
      float tc = tanhf(cn);
      size_t idx=(size_t)b*512+j;
      if(b<bt){ hout[idx]=f2bf(ov*tc); creg[m][jj]=cn; }
      else    { hout[idx]=hprev[idx]; }
      stt[idx]=f2bf(sv*tc);
    }
  }
}

// ---------- device attention for one batch row (all bf16 inputs) ----------
DEVI void dev_attn(float* sS, float* sA, int b, const PCtx& p,
                   const unsigned short* satt, const unsigned short* hatt,
                   const unsigned short* scs, const unsigned short* sch,
                   unsigned short* outl){
  int tid=threadIdx.x; int gid=tid>>4, gl=tid&15;
  const unsigned short* ha = hatt + (size_t)b*512;
  #pragma unroll
  for(int rp=0;rp<4;rp++){
    int pp = rp*16 + gid;
    float s = 0.f;
    if(pp<50){
      const unsigned short* vp = (pp<NPIX) ? (p.vattn + ((size_t)b*NPIX + pp)*512)
                                           : (satt + (size_t)b*512);
      for(int k=gl*32;k<gl*32+32;k++) s += tanhf(bf2f(vp[k]) + bf2f(ha[k])) * p.alW[k];
    }
    #pragma unroll
    for(int off=8;off>=1;off>>=1) s += __shfl_xor(s, off);
    if(gl==0 && pp<50) sS[pp] = s + p.alb[0];
  }
  __syncthreads();
  if(tid==0){
    float m=-1e30f;
    for(int pp=0;pp<50;pp++) m = fmaxf(m, sS[pp]);
    float sum=0.f;
    for(int pp=0;pp<50;pp++){ float e=expf(sS[pp]-m); sA[pp]=e; sum+=e; }
    float inv=1.f/sum;
    for(int pp=0;pp<50;pp++) sA[pp]*=inv;
  }
  __syncthreads();
  float a49 = sA[49];
  for(int n=tid;n<512;n+=256){
    float acc = bf2f(sch[(size_t)b*512+n]) + a49*bf2f(scs[(size_t)b*512+n]) + p.cxb[n];
    const unsigned short* sp = p.SC + (size_t)b*NPIX*512 + n;
    for(int pp=0;pp<NPIX;pp++) acc += sA[pp]*bf2f(sp[(size_t)pp*512]);
    outl[(size_t)b*512+n] = f2bf(tanhf(acc));
  }
  __syncthreads();
}

// ---------- device fc tile (64 vocab cols) ----------
DEVI void dev_fc(unsigned short (*As)[136], const PCtx& p, int t, int xtile,
                 const unsigned short* outl){
  int tid=threadIdx.x, wave=tid>>6, lane=tid&63, l15=lane&15, l4=lane>>4;
  int bt = p.Bt[t];
  f32x4 acc[8];
  f32x4 z = {0.f,0.f,0.f,0.f};
  #pragma unroll
  for(int i=0;i<8;i++) acc[i]=z;
  int cch=tid&15, r0=tid>>4;
  int nbase = xtile*64 + wave*16;
  int nr = nbase + l15; if(nr > VOCAB-1) nr = VOCAB-1;
  for(int kc=0;kc<512;kc+=128){
    __syncthreads();
    #pragma unroll
    for(int rp=0;rp<8;rp++){
      int r=r0+rp*16;
      *(uint4*)&As[r][cch*8] = *(const uint4*)(outl + (size_t)r*512 + kc + cch*8);
    }
    __syncthreads();
    #pragma unroll
    for(int kk=0;kk<4;kk++){
      bf16x8 bfr = *(const bf16x8*)(p.w_fc + (size_t)nr*512 + kc + kk*32 + l4*8);
      #pragma unroll
      for(int mt=0;mt<8;mt++){
        if(mt*16 < bt){
          bf16x8 af = *(const bf16x8*)&As[mt*16+l15][kk*32+l4*8];
          acc[mt]=mfma16(af,bfr,acc[mt]);
        }
      }
    }
  }
  int n = nbase + l15; bool nok = n < VOCAB;
  float bs = nok ? p.fcb[n] : 0.f;
  #pragma unroll
  for(int mt=0;mt<8;mt++){
    #pragma unroll
    for(int j=0;j<4;j++){
      int b = mt*16 + l4*4 + j;
      float v = (b<bt) ? (acc[mt][j]+bs) : 0.f;
      if(nok) p.dout[(size_t)b*(TT*VOCAB) + (size_t)t*VOCAB + n] = v;
    }
  }
  __syncthreads();
}

// ---------- the persistent kernel: L-group (0-31) + 7 teams of 32 ----------
__global__ __launch_bounds__(256) void k_persist(PCtx p){
  __shared__ unsigned short As[128][136];
  __shared__ float sS[52];
  __shared__ float sA[52];
  int cb = blockIdx.x;
  if(cb < 32){
    // LSTM chain
    float creg[2][4];
    #pragma unroll
    for(int m=0;m<2;m++)
      #pragma unroll
      for(int j=0;j<4;j++) creg[m][j]=0.f;
    for(int t=0;t<TT;t++){
      if(t>0) waitflags(p.Lflag, t);
      dev_lstm(As, p, t, cb, p.h_hist + (size_t)t*SLOT, p.h_hist + (size_t)(t+1)*SLOT, creg);
      signal(&p.Lflag[cb], t+1);
    }
  } else {
    int team = (cb-32)>>5, w = (cb-32)&31;
    unsigned short* S = p.tbuf + (size_t)team*7*SLOT;
    unsigned short *Saff=S, *Haff=S+SLOT, *Outl=S+2*SLOT, *Satt=S+3*SLOT,
                   *Hatt=S+4*SLOT, *Scs=S+5*SLOT, *Sch=S+6*SLOT;
    int* tf = p.Tflag + team*32;
    int it=0;
    for(int t=team; t<TT; t+=7, it++){
      waitflags(p.Lflag, t+1);
      // A: aff
      if(w<8)       dev_gemm512(As, p.stb + (size_t)t*SLOT,        p.w_saff, p.sab, Saff, 1, w,   0);
      else if(w<16) dev_gemm512(As, p.h_hist + (size_t)(t+1)*SLOT, p.w_haff, p.hab, Haff, 2, w-8, 0);
      signal(&tf[w], it*3+1); waitflags(tf, it*3+1);
      // B: att projections
      if(w<8)       dev_gemm512(As, Saff, p.w_satt, p.stbias, Satt, 0, w,    0);
      else if(w<16) dev_gemm512(As, Haff, p.w_hatt, p.htb,    Hatt, 0, w-8,  0);
      else if(w<24) dev_gemm512(As, Saff, p.w_ctx,  nullptr,  Scs,  0, w-16, 0);
      else          dev_gemm512(As, Haff, p.w_ctx,  nullptr,  Sch,  0, w-24, 0);
      signal(&tf[w], it*3+2); waitflags(tf, it*3+2);
      // C: attention (4 rows per block)
      for(int r=0;r<4;r++) dev_attn(sS, sA, w*4+r, p, Satt, Hatt, Scs, Sch, Outl);
      signal(&tf[w], it*3+3); waitflags(tf, it*3+3);
      // D: fc tiles
      for(int x=w; x<157; x+=32) dev_fc(As, p, t, x, Outl);
    }
  }
}

// ---------- host launch ----------
extern "C" void kernel_launch(void* const* d_in, const int* in_sizes, int n_in,
                              void* d_out, int out_size, void* d_ws, size_t ws_size,
                              hipStream_t stream)
{
  const float* enc  =(const float*)d_in[0];
  const float* gfeat=(const float*)d_in[1];
  const int*   caps =(const int*)d_in[2];
  const int*   lens =(const int*)d_in[3];
  const float* embW =(const float*)d_in[4];
  const float* e2hW =(const float*)d_in[5];  const float* e2hb=(const float*)d_in[6];
  const float* gfW  =(const float*)d_in[7];  const float* gfb =(const float*)d_in[8];
  const float* fcW  =(const float*)d_in[9];  const float* fcb =(const float*)d_in[10];
  const float* WihF =(const float*)d_in[11]; const float* bih =(const float*)d_in[12];
  const float* WhhF =(const float*)d_in[13]; const float* bhh =(const float*)d_in[14];
  const float* xgWF =(const float*)d_in[15]; const float* bxg =(const float*)d_in[16];
  const float* hgWF =(const float*)d_in[17]; const float* bhg =(const float*)d_in[18];
  const float* saWF =(const float*)d_in[19]; const float* sab =(const float*)d_in[20];
  const float* stWF =(const float*)d_in[21]; const float* stbias=(const float*)d_in[22];
  const float* haWF =(const float*)d_in[23]; const float* hab =(const float*)d_in[24];
  const float* htWF =(const float*)d_in[25]; const float* htb =(const float*)d_in[26];
  const float* vaWF =(const float*)d_in[27]; const float* vab =(const float*)d_in[28];
  const float* alW  =(const float*)d_in[29]; const float* alb =(const float*)d_in[30];
  const float* cxWF =(const float*)d_in[31]; const float* cxb =(const float*)d_in[32];

  char* base=(char*)d_ws; size_t off=0;
  auto alloc=[&](size_t bytes)->void*{ void* r=base+off; off += (bytes+255)&~(size_t)255; return r; };

  int* order=(int*)alloc(BB*4);
  int* Bt   =(int*)alloc(32*4);
  unsigned short* w_e2h =(unsigned short*)alloc((size_t)512*2048*2);   // aliased by stb_hist in persist
  unsigned short* w_gf  =(unsigned short*)alloc((size_t)512*2048*2);   // (contiguous with w_e2h)
  unsigned short* w_fc  =(unsigned short*)alloc((size_t)VOCAB*512*2);
  unsigned short* w_ih  =(unsigned short*)alloc((size_t)2048*1024*2);
  unsigned short* w_hh  =(unsigned short*)alloc((size_t)2048*512*2);
  unsigned short* w_xg  =(unsigned short*)alloc((size_t)512*1024*2);
  unsigned short* w_hg  =(unsigned short*)alloc((size_t)512*512*2);
  unsigned short* w_saff=(unsigned short*)alloc((size_t)512*512*2);
  unsigned short* w_satt=(unsigned short*)alloc((size_t)512*512*2);
  unsigned short* w_haff=(unsigned short*)alloc((size_t)512*512*2);
  unsigned short* w_hatt=(unsigned short*)alloc((size_t)512*512*2);
  unsigned short* w_vatt=(unsigned short*)alloc((size_t)512*512*2);
  unsigned short* w_ctx =(unsigned short*)alloc((size_t)512*512*2);
  unsigned short* spatial=(unsigned short*)alloc((size_t)BB*NPIX*512*2); // aliased by h_hist in persist
  unsigned short* vattn  =(unsigned short*)alloc((size_t)BB*NPIX*512*2);
  unsigned short* SC     =(unsigned short*)alloc((size_t)BB*NPIX*512*2);
  unsigned short* gimg   =(unsigned short*)alloc((size_t)BB*512*2);
  unsigned short* xt     =(unsigned short*)alloc((size_t)BB*TT*1024*2);
  int* flags =(int*)alloc(4096);                 // Lflag[32] @0, Tflag[7*32] @64
  unsigned short* tbuf=(unsigned short*)alloc((size_t)7*7*SLOT*2);

  unsigned short* stb_hist = w_e2h;              // 30*SLOT*2 = 3.93MB <= 4MB (w_e2h+w_gf)
  unsigned short* h_hist   = spatial;            // 31*SLOT*2 = 4.06MB <= 6.42MB

  k_sort<<<1,BB,0,stream>>>(lens, order, Bt);

  WC13 wc;
  const float* srcs[13] = {e2hW,gfW,fcW,WihF,WhhF,xgWF,hgWF,saWF,stWF,haWF,htWF,vaWF,cxWF};
  unsigned short* dsts[13] = {w_e2h,w_gf,w_fc,w_ih,w_hh,w_xg,w_hg,w_saff,w_satt,w_haff,w_hatt,w_vatt,w_ctx};
  int ns[13] = {512*2048,512*2048,VOCAB*512,2048*1024,2048*512,512*1024,512*512,512*512,512*512,512*512,512*512,512*512,512*512};
  for(int i=0;i<13;i++){ wc.src[i]=srcs[i]; wc.dst[i]=dsts[i]; wc.n[i]=ns[i]; }
  k_wconv<<<1024,256,0,stream>>>(wc);

  // spatial / gimg / xt / vattn / SC precompute
  k_gemm_f32A2<<<dim3(2,NPIX),256,0,stream>>>(enc, ENCD, NPIX, order, w_e2h, e2hb, spatial, ENCD);
  k_gemm_f32A2<<<dim3(2,1),  256,0,stream>>>(gfeat, ENCD, 1, order, w_gf, gfb, gimg, ENCD);
  k_xt<<<1024,256,0,stream>>>(caps, order, embW, gimg, xt);
  {
    PreD2 dv{};
    dv.d[0] = PreD{spatial, w_vatt, vab,     vattn};
    dv.d[1] = PreD{spatial, w_ctx,  nullptr, SC};
    k_pre<<<dim3(8,NPIX,2),256,0,stream>>>(dv);
  }

  // zero h slot 0 and flags (after precompute reads of spatial/w_e2h are ordered on stream)
  hipMemsetAsync(h_hist, 0, (size_t)SLOT*2, stream);
  hipMemsetAsync(flags, 0, 4096, stream);

  PCtx pc;
  pc.xt=xt; pc.w_ih=w_ih; pc.w_hh=w_hh; pc.w_xg=w_xg; pc.w_hg=w_hg;
  pc.w_saff=w_saff; pc.w_satt=w_satt; pc.w_haff=w_haff; pc.w_hatt=w_hatt; pc.w_ctx=w_ctx; pc.w_fc=w_fc;
  pc.vattn=vattn; pc.SC=SC;
  pc.bih=bih; pc.bhh=bhh; pc.bxg=bxg; pc.bhg=bhg;
  pc.sab=sab; pc.stbias=stbias; pc.hab=hab; pc.htb=htb;
  pc.alW=alW; pc.alb=alb; pc.cxb=cxb; pc.fcb=fcb;
  pc.Bt=Bt;
  pc.h_hist=h_hist; pc.stb=stb_hist; pc.tbuf=tbuf;
  pc.dout=(float*)d_out;
  pc.Lflag=flags; pc.Tflag=flags+64;

  k_persist<<<256,256,0,stream>>>(pc);
}

// Round 4
// 2402.623 us; speedup vs baseline: 3.2239x; 1.1707x over previous
//
#include <hip/hip_runtime.h>
#include <hip/hip_bf16.h>
#include <cstdint>
#include <cstddef>

#define DEVI __device__ __forceinline__

// ---------- constants ----------
#define BB 128
#define TT 30
#define VOCAB 10000
#define ENCD 2048
#define NPIX 49
#define SLOT 65536   // 128*512 elements

typedef __attribute__((ext_vector_type(8))) short bf16x8;
typedef __attribute__((ext_vector_type(4))) float f32x4;

DEVI float bf2f(unsigned short u){ union{float f; unsigned int i;} x; x.i=((unsigned)u)<<16; return x.f; }
DEVI unsigned short f2bf(float f){ union{float f; unsigned int i;} x; x.f=f; unsigned r=x.i + 0x7fffu + ((x.i>>16)&1u); return (unsigned short)(r>>16); }
DEVI float sigm(float x){ return 1.0f/(1.0f+expf(-x)); }
DEVI f32x4 mfma16(bf16x8 a, bf16x8 b, f32x4 c){ return __builtin_amdgcn_mfma_f32_16x16x32_bf16(a,b,c,0,0,0); }

// ---------- cache-bypassing (coherence-point) loads for cross-block data ----------
DEVI uint4 byp16(const void* p){
  const unsigned long long* q=(const unsigned long long*)p;
  unsigned long long a=__hip_atomic_load(q,   __ATOMIC_RELAXED, __HIP_MEMORY_SCOPE_AGENT);
  unsigned long long b=__hip_atomic_load(q+1, __ATOMIC_RELAXED, __HIP_MEMORY_SCOPE_AGENT);
  uint4 r; r.x=(unsigned)a; r.y=(unsigned)(a>>32); r.z=(unsigned)b; r.w=(unsigned)(b>>32); return r;
}
DEVI unsigned byp4(const void* p){
  return __hip_atomic_load((const unsigned*)p, __ATOMIC_RELAXED, __HIP_MEMORY_SCOPE_AGENT);
}

// ---------- flag sync: NO acquire fence (readers use bypass loads for data) ----------
DEVI void waitflags(int* flags, int thresh){
  __syncthreads();
  if(threadIdx.x < 64){
    for(;;){
      int v = (threadIdx.x<32) ? __hip_atomic_load(&flags[threadIdx.x], __ATOMIC_RELAXED, __HIP_MEMORY_SCOPE_AGENT)
                               : 0x7fffffff;
      if(__all(v >= thresh)) break;
      __builtin_amdgcn_s_sleep(1);
    }
  }
  asm volatile("" ::: "memory");
  __syncthreads();
}
DEVI void signal(int* flag, int val){
  __syncthreads();   // all waves' stores drained to L2 before thread 0's release
  if(threadIdx.x==0) __hip_atomic_store(flag, val, __ATOMIC_RELEASE, __HIP_MEMORY_SCOPE_AGENT); // waitcnt + wbl2 + store
}

// ---------- sort: stable descending by length ----------
__global__ void k_sort(const int* __restrict__ lens, int* __restrict__ order, int* __restrict__ Bt){
  __shared__ int L[BB];
  int i = threadIdx.x;
  L[i] = lens[i];
  __syncthreads();
  int li = L[i]; int rank = 0;
  for(int j=0;j<BB;j++){ int lj=L[j]; rank += (lj>li) || (lj==li && j<i); }
  order[rank] = i;
  if(i<TT){ int c=0; for(int j=0;j<BB;j++) c += (L[j]>i); Bt[i]=c; }
}

// ---------- weight f32 -> bf16 conversion ----------
struct WC13 { const float* src[13]; unsigned short* dst[13]; int n[13]; };
__global__ void k_wconv(WC13 wc){
  int stride = gridDim.x*blockDim.x;
  int tid0 = blockIdx.x*blockDim.x + threadIdx.x;
  for(int s=0;s<13;s++){
    const float4* src=(const float4*)wc.src[s];
    int n4 = wc.n[s]>>2;
    ushort4* dst=(ushort4*)wc.dst[s];
    for(int i=tid0;i<n4;i+=stride){
      float4 v=src[i];
      ushort4 o; o.x=f2bf(v.x); o.y=f2bf(v.y); o.z=f2bf(v.z); o.w=f2bf(v.w);
      dst[i]=o;
    }
  }
}

// ---------- xt build ----------
__global__ void k_xt(const int* __restrict__ caps, const int* __restrict__ order,
                     const float* __restrict__ embW, const unsigned short* __restrict__ gimg,
                     unsigned short* __restrict__ xt){
  int total=BB*TT*1024;
  for(int idx=blockIdx.x*blockDim.x+threadIdx.x; idx<total; idx+=gridDim.x*blockDim.x){
    int k=idx&1023; int bt=idx>>10; int t=bt%TT; int b=bt/TT;
    unsigned short v;
    if(k<512){ int tok=caps[order[b]*TT+t]; v=f2bf(embW[(size_t)tok*512+k]); }
    else v=gimg[b*512+(k-512)];
    xt[idx]=v;
  }
}

// ---------- GEMM, f32 A row-reordered -> bf16, 256-col tiles ----------
__global__ __launch_bounds__(256) void k_gemm_f32A2(
    const float* __restrict__ A, int lda, int rpb, const int* __restrict__ order,
    const unsigned short* __restrict__ W, const float* __restrict__ bias,
    unsigned short* __restrict__ out, int K)
{
  __shared__ unsigned short As[128][136];
  int tid=threadIdx.x, wave=tid>>6, lane=tid&63, l15=lane&15, l4=lane>>4;
  int mb = blockIdx.y*128;
  f32x4 acc[8][4];
  f32x4 z = {0.f,0.f,0.f,0.f};
  #pragma unroll
  for(int i=0;i<8;i++)
    #pragma unroll
    for(int j=0;j<4;j++) acc[i][j]=z;
  int cch=tid&15, r0=tid>>4;
  int nb = blockIdx.x*256 + wave*64;
  for(int kc=0;kc<K;kc+=128){
    __syncthreads();
    #pragma unroll
    for(int rp=0;rp<8;rp++){
      int r=r0+rp*16;
      int m=mb+r;
      int sb = order[m/rpb]*rpb + m%rpb;
      const float* p = A + (size_t)sb*lda + kc + cch*8;
      float4 v0=*(const float4*)p, v1=*(const float4*)(p+4);
      unsigned short* d=&As[r][cch*8];
      d[0]=f2bf(v0.x); d[1]=f2bf(v0.y); d[2]=f2bf(v0.z); d[3]=f2bf(v0.w);
      d[4]=f2bf(v1.x); d[5]=f2bf(v1.y); d[6]=f2bf(v1.z); d[7]=f2bf(v1.w);
    }
    __syncthreads();
    #pragma unroll
    for(int kk=0;kk<4;kk++){
      bf16x8 bfr[4];
      #pragma unroll
      for(int nt=0;nt<4;nt++)
        bfr[nt] = *(const bf16x8*)(W + (size_t)(nb+nt*16+l15)*K + kc + kk*32 + l4*8);
      #pragma unroll
      for(int mt=0;mt<8;mt++){
        bf16x8 af = *(const bf16x8*)&As[mt*16+l15][kk*32+l4*8];
        #pragma unroll
        for(int nt=0;nt<4;nt++) acc[mt][nt]=mfma16(af,bfr[nt],acc[mt][nt]);
      }
    }
  }
  #pragma unroll
  for(int nt=0;nt<4;nt++){
    int n = nb + nt*16 + l15;
    float bs = bias[n];
    #pragma unroll
    for(int mt=0;mt<8;mt++){
      #pragma unroll
      for(int j=0;j<4;j++){
        int row = mb + mt*16 + l4*4 + j;
        float v = acc[mt][nt][j]+bs; v = v>0.f ? v : 0.f;
        out[(size_t)row*512 + n] = f2bf(v);
      }
    }
  }
}

// ---------- device GEMM: bf16 A (ld 512), bf16 W (512x512); BYP=1 -> A via bypass loads ----------
template<int BYP>
DEVI void dev_gemm512(unsigned short (*As)[136], const unsigned short* A, const unsigned short* W,
                      const float* bias, unsigned short* out, int act, int xtile, int mb){
  int tid=threadIdx.x, wave=tid>>6, lane=tid&63, l15=lane&15, l4=lane>>4;
  f32x4 acc[8];
  f32x4 z = {0.f,0.f,0.f,0.f};
  #pragma unroll
  for(int i=0;i<8;i++) acc[i]=z;
  int cch=tid&15, r0=tid>>4;
  int nrow = xtile*64 + wave*16 + l15;
  for(int kc=0;kc<512;kc+=128){
    __syncthreads();
    #pragma unroll
    for(int rp=0;rp<8;rp++){
      int r=r0+rp*16;
      const unsigned short* src = A + (size_t)(mb+r)*512 + kc + cch*8;
      if(BYP) *(uint4*)&As[r][cch*8] = byp16(src);
      else    *(uint4*)&As[r][cch*8] = *(const uint4*)src;
    }
    __syncthreads();
    #pragma unroll
    for(int kk=0;kk<4;kk++){
      bf16x8 bfr = *(const bf16x8*)(W + (size_t)nrow*512 + kc + kk*32 + l4*8);
      #pragma unroll
      for(int mt=0;mt<8;mt++){
        bf16x8 af = *(const bf16x8*)&As[mt*16+l15][kk*32+l4*8];
        acc[mt]=mfma16(af,bfr,acc[mt]);
      }
    }
  }
  float bs = bias ? bias[nrow] : 0.f;
  #pragma unroll
  for(int mt=0;mt<8;mt++){
    #pragma unroll
    for(int j=0;j<4;j++){
      int row = mb + mt*16 + l4*4 + j;
      float v = acc[mt][j]+bs;
      if(act==1) v = fmaxf(v,0.f);
      else if(act==2) v = tanhf(v);
      out[(size_t)row*512+nrow]=f2bf(v);
    }
  }
  __syncthreads();
}

// precompute wrapper (vattn / SC)
struct PreD { const unsigned short* A; const unsigned short* W; const float* bias; unsigned short* out; };
struct PreD2 { PreD d[2]; };
__global__ __launch_bounds__(256) void k_pre(PreD2 dd){
  __shared__ unsigned short As[128][136];
  PreD g = dd.d[blockIdx.z];
  dev_gemm512<0>(As, g.A, g.W, g.bias, g.out, 0, blockIdx.x, blockIdx.y*128);
}

// ---------- persistent-kernel context ----------
struct PCtx {
  const unsigned short *xt, *w_ih, *w_hh, *w_xg, *w_hg;
  const unsigned short *w_saff, *w_satt, *w_haff, *w_hatt, *w_ctx, *w_fc;
  const unsigned short *vattn, *SC;
  const float *bih,*bhh,*bxg,*bhg, *sab,*stbias,*hab,*htb, *alW,*alb, *cxb, *fcb;
  const int *Bt;
  unsigned short *h_hist;   // (TT+1) slots of 128x512 bf16; slot 0 zeroed
  unsigned short *stb;      // TT slots
  unsigned short *tbuf;     // 7 teams x 7 bufs x SLOT
  float *dout;
  int *Lflag;               // [32]
  int *Tflag;               // [7*32]
};

// ---------- device LSTM tile (16 j-cols, 5 strips), c in registers ----------
DEVI void dev_lstm(unsigned short (*As)[136], const PCtx& p, int t, int jblk,
                   const unsigned short* hprev, unsigned short* hout, float creg[2][4]){
  int tid=threadIdx.x, wave=tid>>6, lane=tid&63, l15=lane&15, l4=lane>>4;
  int jb = jblk*16;
  f32x4 acc[2][5];
  f32x4 z = {0.f,0.f,0.f,0.f};
  #pragma unroll
  for(int m=0;m<2;m++)
    #pragma unroll
    for(int s=0;s<5;s++) acc[m][s]=z;
  int cch=tid&15, r0=tid>>4;
  for(int kc=0;kc<1536;kc+=128){
    __syncthreads();
    #pragma unroll
    for(int rp=0;rp<8;rp++){
      int r=r0+rp*16;
      int kg = kc + cch*8;
      if(kg<1024){
        *(uint4*)&As[r][cch*8] = *(const uint4*)(p.xt + (size_t)r*(TT*1024) + t*1024 + kg);
      } else {
        *(uint4*)&As[r][cch*8] = byp16(hprev + (size_t)r*512 + (kg-1024));   // cross-block h
      }
    }
    __syncthreads();
    #pragma unroll
    for(int kk=0;kk<4;kk++){
      int kg = kc + kk*32 + l4*8;
      bf16x8 bfr[5];
      #pragma unroll
      for(int s=0;s<5;s++){
        int row = (s<4) ? (s*512 + jb + l15) : (jb + l15);
        const unsigned short* wp;
        if(s<4) wp = (kg<1024) ? (p.w_ih + (size_t)row*1024 + kg) : (p.w_hh + (size_t)row*512 + (kg-1024));
        else    wp = (kg<1024) ? (p.w_xg + (size_t)row*1024 + kg) : (p.w_hg + (size_t)row*512 + (kg-1024));
        bfr[s] = *(const bf16x8*)wp;
      }
      #pragma unroll
      for(int m=0;m<2;m++){
        int mt = wave*2+m;
        bf16x8 af = *(const bf16x8*)&As[mt*16+l15][kk*32+l4*8];
        #pragma unroll
        for(int s=0;s<5;s++) acc[m][s]=mfma16(af,bfr[s],acc[m][s]);
      }
    }
  }
  int bt = p.Bt[t];
  int j = jb + l15;
  float bi  = p.bih[j]      + p.bhh[j];
  float bff = p.bih[512+j]  + p.bhh[512+j];
  float bg  = p.bih[1024+j] + p.bhh[1024+j];
  float bo  = p.bih[1536+j] + p.bhh[1536+j];
  float bs  = p.bxg[j] + p.bhg[j];
  unsigned short* stt = p.stb + (size_t)t*SLOT;
  #pragma unroll
  for(int m=0;m<2;m++){
    int mt = wave*2+m;
    #pragma unroll
    for(int jj=0;jj<4;jj++){
      int b = mt*16 + l4*4 + jj;
      float iv = sigm(acc[m][0][jj]+bi);
      float fv = sigm(acc[m][1][jj]+bff);
      float gv = tanhf(acc[m][2][jj]+bg);
      float ov = sigm(acc[m][3][jj]+bo);
      float sv = sigm(acc[m][4][jj]+bs);
      float cn = fv*creg[m][jj] + iv*gv;
      float tc = tanhf(cn);
      size_t idx=(size_t)b*512+j;
      if(b<bt){ hout[idx]=f2bf(ov*tc); creg[m][jj]=cn; }
      else {
        // carry h: read old h via bypass (cross-block), 4B-aligned pair, pick half by j parity
        unsigned pr = byp4(hprev + (idx & ~(size_t)1));
        hout[idx] = (j&1) ? (unsigned short)(pr>>16) : (unsigned short)pr;
      }
      stt[idx]=f2bf(sv*tc);
    }
  }
}

// ---------- device attention for one batch row (cross-block bufs via bypass) ----------
DEVI void dev_attn(float* sS, float* sA, int b, const PCtx& p,
                   const unsigned short* satt, const unsigned short* hatt,
                   const unsigned short* scs, const unsigned short* sch,
                   unsigned short* outl){
  int tid=threadIdx.x; int gid=tid>>4, gl=tid&15;
  const unsigned short* ha = hatt + (size_t)b*512;
  #pragma unroll
  for(int rp=0;rp<4;rp++){
    int pp = rp*16 + gid;
    float s = 0.f;
    if(pp<50){
      const unsigned short* vp = p.vattn + ((size_t)b*NPIX + pp)*512;  // cached (pp<49)
      const unsigned short* sa = satt + (size_t)b*512;                 // bypass (pp==49)
      #pragma unroll 4
      for(int kk=0;kk<16;kk++){
        int k = gl*32 + kk*2;
        unsigned hu = byp4(ha + k);
        float h0=bf2f((unsigned short)hu), h1=bf2f((unsigned short)(hu>>16));
        float a0,a1;
        if(pp<NPIX){ a0=bf2f(vp[k]); a1=bf2f(vp[k+1]); }
        else { unsigned su=byp4(sa + k); a0=bf2f((unsigned short)su); a1=bf2f((unsigned short)(su>>16)); }
        s += tanhf(a0+h0)*p.alW[k] + tanhf(a1+h1)*p.alW[k+1];
      }
    }
    #pragma unroll
    for(int off=8;off>=1;off>>=1) s += __shfl_xor(s, off);
    if(gl==0 && pp<50) sS[pp] = s + p.alb[0];
  }
  __syncthreads();
  if(tid<64){
    float sv = (tid<50) ? sS[tid] : -1e30f;
    float m = sv;
    #pragma unroll
    for(int off=32;off>=1;off>>=1) m = fmaxf(m, __shfl_xor(m, off));
    float e = (tid<50) ? expf(sv-m) : 0.f;
    float sum = e;
    #pragma unroll
    for(int off=32;off>=1;off>>=1) sum += __shfl_xor(sum, off);
    if(tid<50) sA[tid] = e/sum;
  }
  __syncthreads();
  float a49 = sA[49];
  {
    int n0 = tid*2;
    unsigned schU = byp4(sch + (size_t)b*512 + n0);
    unsigned scsU = byp4(scs + (size_t)b*512 + n0);
    float acc0 = bf2f((unsigned short)schU) + a49*bf2f((unsigned short)(schU>>16))*0.f; // placeholder fix below
    // correct unpack:
    float c0 = bf2f((unsigned short)schU), c1 = bf2f((unsigned short)(schU>>16));
    float s0 = bf2f((unsigned short)scsU), s1 = bf2f((unsigned short)(scsU>>16));
    acc0 = c0 + a49*s0 + p.cxb[n0];
    float acc1 = c1 + a49*s1 + p.cxb[n0+1];
    const unsigned short* sp = p.SC + (size_t)b*NPIX*512 + n0;   // cached
    for(int pp=0;pp<NPIX;pp++){
      unsigned u = *(const unsigned*)(sp + (size_t)pp*512);
      acc0 += sA[pp]*bf2f((unsigned short)u);
      acc1 += sA[pp]*bf2f((unsigned short)(u>>16));
    }
    unsigned o = ((unsigned)f2bf(tanhf(acc1))<<16) | (unsigned)f2bf(tanhf(acc0));
    *(unsigned*)(outl + (size_t)b*512 + n0) = o;
  }
  __syncthreads();
}

// ---------- device fc tile (64 vocab cols), outl staged via bypass ----------
DEVI void dev_fc(unsigned short (*As)[136], const PCtx& p, int t, int xtile,
                 const unsigned short* outl){
  int tid=threadIdx.x, wave=tid>>6, lane=tid&63, l15=lane&15, l4=lane>>4;
  int bt = p.Bt[t];
  f32x4 acc[8];
  f32x4 z = {0.f,0.f,0.f,0.f};
  #pragma unroll
  for(int i=0;i<8;i++) acc[i]=z;
  int cch=tid&15, r0=tid>>4;
  int nbase = xtile*64 + wave*16;
  int nr = nbase + l15; if(nr > VOCAB-1) nr = VOCAB-1;
  for(int kc=0;kc<512;kc+=128){
    __syncthreads();
    #pragma unroll
    for(int rp=0;rp<8;rp++){
      int r=r0+rp*16;
      *(uint4*)&As[r][cch*8] = byp16(outl + (size_t)r*512 + kc + cch*8);
    }
    __syncthreads();
    #pragma unroll
    for(int kk=0;kk<4;kk++){
      bf16x8 bfr = *(const bf16x8*)(p.w_fc + (size_t)nr*512 + kc + kk*32 + l4*8);
      #pragma unroll
      for(int mt=0;mt<8;mt++){
        if(mt*16 < bt){
          bf16x8 af = *(const bf16x8*)&As[mt*16+l15][kk*32+l4*8];
          acc[mt]=mfma16(af,bfr,acc[mt]);
        }
      }
    }
  }
  int n = nbase + l15; bool nok = n < VOCAB;
  float bs = nok ? p.fcb[n] : 0.f;
  #pragma unroll
  for(int mt=0;mt<8;mt++){
    #pragma unroll
    for(int j=0;j<4;j++){
      int b = mt*16 + l4*4 + j;
      float v = (b<bt) ? (acc[mt][j]+bs) : 0.f;
      if(nok) p.dout[(size_t)b*(TT*VOCAB) + (size_t)t*VOCAB + n] = v;
    }
  }
  __syncthreads();
}

// ---------- the persistent kernel: L-group (0-31) + 7 teams of 32 ----------
__global__ __launch_bounds__(256) void k_persist(PCtx p){
  __shared__ unsigned short As[128][136];
  __shared__ float sS[52];
  __shared__ float sA[52];
  int cb = blockIdx.x;
  if(cb < 32){
    // LSTM chain
    float creg[2][4];
    #pragma unroll
    for(int m=0;m<2;m++)
      #pragma unroll
      for(int j=0;j<4;j++) creg[m][j]=0.f;
    for(int t=0;t<TT;t++){
      if(t>0) waitflags(p.Lflag, t);
      dev_lstm(As, p, t, cb, p.h_hist + (size_t)t*SLOT, p.h_hist + (size_t)(t+1)*SLOT, creg);
      signal(&p.Lflag[cb], t+1);
    }
  } else {
    int team = (cb-32)>>5, w = (cb-32)&31;
    unsigned short* S = p.tbuf + (size_t)team*7*SLOT;
    unsigned short *Saff=S, *Haff=S+SLOT, *Outl=S+2*SLOT, *Satt=S+3*SLOT,
                   *Hatt=S+4*SLOT, *Scs=S+5*SLOT, *Sch=S+6*SLOT;
    int* tf = p.Tflag + team*32;
    int it=0;
    for(int t=team; t<TT; t+=7, it++){
      waitflags(p.Lflag, t+1);
      // A: aff
      if(w<8)       dev_gemm512<1>(As, p.stb + (size_t)t*SLOT,        p.w_saff, p.sab, Saff, 1, w,   0);
      else if(w<16) dev_gemm512<1>(As, p.h_hist + (size_t)(t+1)*SLOT, p.w_haff, p.hab, Haff, 2, w-8, 0);
      signal(&tf[w], it*3+1); waitflags(tf, it*3+1);
      // B: att projections
      if(w<8)       dev_gemm512<1>(As, Saff, p.w_satt, p.stbias, Satt, 0, w,    0);
      else if(w<16) dev_gemm512<1>(As, Haff, p.w_hatt, p.htb,    Hatt, 0, w-8,  0);
      else if(w<24) dev_gemm512<1>(As, Saff, p.w_ctx,  nullptr,  Scs,  0, w-16, 0);
      else          dev_gemm512<1>(As, Haff, p.w_ctx,  nullptr,  Sch,  0, w-24, 0);
      signal(&tf[w], it*3+2); waitflags(tf, it*3+2);
      // C: attention (4 rows per block)
      for(int r=0;r<4;r++) dev_attn(sS, sA, w*4+r, p, Satt, Hatt, Scs, Sch, Outl);
      signal(&tf[w], it*3+3); waitflags(tf, it*3+3);
      // D: fc tiles
      for(int x=w; x<157; x+=32) dev_fc(As, p, t, x, Outl);
    }
  }
}

// ---------- host launch ----------
extern "C" void kernel_launch(void* const* d_in, const int* in_sizes, int n_in,
                              void* d_out, int out_size, void* d_ws, size_t ws_size,
                              hipStream_t stream)
{
  const float* enc  =(const float*)d_in[0];
  const float* gfeat=(const float*)d_in[1];
  const int*   caps =(const int*)d_in[2];
  const int*   lens =(const int*)d_in[3];
  const float* embW =(const float*)d_in[4];
  const float* e2hW =(const float*)d_in[5];  const float* e2hb=(const float*)d_in[6];
  const float* gfW  =(const float*)d_in[7];  const float* gfb =(const float*)d_in[8];
  const float* fcW  =(const float*)d_in[9];  const float* fcb =(const float*)d_in[10];
  const float* WihF =(const float*)d_in[11]; const float* bih =(const float*)d_in[12];
  const float* WhhF =(const float*)d_in[13]; const float* bhh =(const float*)d_in[14];
  const float* xgWF =(const float*)d_in[15]; const float* bxg =(const float*)d_in[16];
  const float* hgWF =(const float*)d_in[17]; const float* bhg =(const float*)d_in[18];
  const float* saWF =(const float*)d_in[19]; const float* sab =(const float*)d_in[20];
  const float* stWF =(const float*)d_in[21]; const float* stbias=(const float*)d_in[22];
  const float* haWF =(const float*)d_in[23]; const float* hab =(const float*)d_in[24];
  const float* htWF =(const float*)d_in[25]; const float* htb =(const float*)d_in[26];
  const float* vaWF =(const float*)d_in[27]; const float* vab =(const float*)d_in[28];
  const float* alW  =(const float*)d_in[29]; const float* alb =(const float*)d_in[30];
  const float* cxWF =(const float*)d_in[31]; const float* cxb =(const float*)d_in[32];

  char* base=(char*)d_ws; size_t off=0;
  auto alloc=[&](size_t bytes)->void*{ void* r=base+off; off += (bytes+255)&~(size_t)255; return r; };

  int* order=(int*)alloc(BB*4);
  int* Bt   =(int*)alloc(32*4);
  unsigned short* w_e2h =(unsigned short*)alloc((size_t)512*2048*2);   // aliased by stb_hist in persist
  unsigned short* w_gf  =(unsigned short*)alloc((size_t)512*2048*2);   // (contiguous with w_e2h)
  unsigned short* w_fc  =(unsigned short*)alloc((size_t)VOCAB*512*2);
  unsigned short* w_ih  =(unsigned short*)alloc((size_t)2048*1024*2);
  unsigned short* w_hh  =(unsigned short*)alloc((size_t)2048*512*2);
  unsigned short* w_xg  =(unsigned short*)alloc((size_t)512*1024*2);
  unsigned short* w_hg  =(unsigned short*)alloc((size_t)512*512*2);
  unsigned short* w_saff=(unsigned short*)alloc((size_t)512*512*2);
  unsigned short* w_satt=(unsigned short*)alloc((size_t)512*512*2);
  unsigned short* w_haff=(unsigned short*)alloc((size_t)512*512*2);
  unsigned short* w_hatt=(unsigned short*)alloc((size_t)512*512*2);
  unsigned short* w_vatt=(unsigned short*)alloc((size_t)512*512*2);
  unsigned short* w_ctx =(unsigned short*)alloc((size_t)512*512*2);
  unsigned short* spatial=(unsigned short*)alloc((size_t)BB*NPIX*512*2); // aliased by h_hist in persist
  unsigned short* vattn  =(unsigned short*)alloc((size_t)BB*NPIX*512*2);
  unsigned short* SC     =(unsigned short*)alloc((size_t)BB*NPIX*512*2);
  unsigned short* gimg   =(unsigned short*)alloc((size_t)BB*512*2);
  unsigned short* xt     =(unsigned short*)alloc((size_t)BB*TT*1024*2);
  int* flags =(int*)alloc(4096);                 // Lflag[32] @0, Tflag[7*32] @64
  unsigned short* tbuf=(unsigned short*)alloc((size_t)7*7*SLOT*2);

  unsigned short* stb_hist = w_e2h;              // 30*SLOT*2 = 3.93MB <= 4MB (w_e2h+w_gf)
  unsigned short* h_hist   = spatial;            // 31*SLOT*2 = 4.06MB <= 6.42MB

  k_sort<<<1,BB,0,stream>>>(lens, order, Bt);

  WC13 wc;
  const float* srcs[13] = {e2hW,gfW,fcW,WihF,WhhF,xgWF,hgWF,saWF,stWF,haWF,htWF,vaWF,cxWF};
  unsigned short* dsts[13] = {w_e2h,w_gf,w_fc,w_ih,w_hh,w_xg,w_hg,w_saff,w_satt,w_haff,w_hatt,w_vatt,w_ctx};
  int ns[13] = {512*2048,512*2048,VOCAB*512,2048*1024,2048*512,512*1024,512*512,512*512,512*512,512*512,512*512,512*512,512*512};
  for(int i=0;i<13;i++){ wc.src[i]=srcs[i]; wc.dst[i]=dsts[i]; wc.n[i]=ns[i]; }
  k_wconv<<<1024,256,0,stream>>>(wc);

  // spatial / gimg / xt / vattn / SC precompute
  k_gemm_f32A2<<<dim3(2,NPIX),256,0,stream>>>(enc, ENCD, NPIX, order, w_e2h, e2hb, spatial, ENCD);
  k_gemm_f32A2<<<dim3(2,1),  256,0,stream>>>(gfeat, ENCD, 1, order, w_gf, gfb, gimg, ENCD);
  k_xt<<<1024,256,0,stream>>>(caps, order, embW, gimg, xt);
  {
    PreD2 dv{};
    dv.d[0] = PreD{spatial, w_vatt, vab,     vattn};
    dv.d[1] = PreD{spatial, w_ctx,  nullptr, SC};
    k_pre<<<dim3(8,NPIX,2),256,0,stream>>>(dv);
  }

  // zero h slot 0 and flags (stream-ordered after precompute reads of spatial/w_e2h)
  hipMemsetAsync(h_hist, 0, (size_t)SLOT*2, stream);
  hipMemsetAsync(flags, 0, 4096, stream);

  PCtx pc;
  pc.xt=xt; pc.w_ih=w_ih; pc.w_hh=w_hh; pc.w_xg=w_xg; pc.w_hg=w_hg;
  pc.w_saff=w_saff; pc.w_satt=w_satt; pc.w_haff=w_haff; pc.w_hatt=w_hatt; pc.w_ctx=w_ctx; pc.w_fc=w_fc;
  pc.vattn=vattn; pc.SC=SC;
  pc.bih=bih; pc.bhh=bhh; pc.bxg=bxg; pc.bhg=bhg;
  pc.sab=sab; pc.stbias=stbias; pc.hab=hab; pc.htb=htb;
  pc.alW=alW; pc.alb=alb; pc.cxb=cxb; pc.fcb=fcb;
  pc.Bt=Bt;
  pc.h_hist=h_hist; pc.stb=stb_hist; pc.tbuf=tbuf;
  pc.dout=(float*)d_out;
  pc.Lflag=flags; pc.Tflag=flags+64;

  k_persist<<<256,256,0,stream>>>(pc);
}

// Round 5
// 2289.738 us; speedup vs baseline: 3.3828x; 1.0493x over previous
//
#include <hip/hip_runtime.h>
#include <hip/hip_bf16.h>
#include <cstdint>
#include <cstddef>

#define DEVI __device__ __forceinline__

// ---------- constants ----------
#define BB 128
#define TT 30
#define VOCAB 10000
#define ENCD 2048
#define NPIX 49
#define SLOT 65536   // 128*512 elements

typedef __attribute__((ext_vector_type(8))) short bf16x8;
typedef __attribute__((ext_vector_type(4))) float f32x4;

DEVI float bf2f(unsigned short u){ union{float f; unsigned int i;} x; x.i=((unsigned)u)<<16; return x.f; }
DEVI unsigned short f2bf(float f){ union{float f; unsigned int i;} x; x.f=f; unsigned r=x.i + 0x7fffu + ((x.i>>16)&1u); return (unsigned short)(r>>16); }
DEVI float sigm(float x){ return 1.0f/(1.0f+expf(-x)); }
DEVI f32x4 mfma16(bf16x8 a, bf16x8 b, f32x4 c){ return __builtin_amdgcn_mfma_f32_16x16x32_bf16(a,b,c,0,0,0); }

// ---------- cache-bypassing (coherence-point) loads for cross-block data ----------
DEVI uint4 byp16(const void* p){
  const unsigned long long* q=(const unsigned long long*)p;
  unsigned long long a=__hip_atomic_load(q,   __ATOMIC_RELAXED, __HIP_MEMORY_SCOPE_AGENT);
  unsigned long long b=__hip_atomic_load(q+1, __ATOMIC_RELAXED, __HIP_MEMORY_SCOPE_AGENT);
  uint4 r; r.x=(unsigned)a; r.y=(unsigned)(a>>32); r.z=(unsigned)b; r.w=(unsigned)(b>>32); return r;
}
DEVI unsigned byp4(const void* p){
  return __hip_atomic_load((const unsigned*)p, __ATOMIC_RELAXED, __HIP_MEMORY_SCOPE_AGENT);
}

// ---------- sync primitives ----------
// short-wait barrier: flag array, parallel release stores, coarse-backoff poll
DEVI void waitflags(int* flags, int thresh){
  __syncthreads();
  if(threadIdx.x < 64){
    for(;;){
      int v = (threadIdx.x<32) ? __hip_atomic_load(&flags[threadIdx.x], __ATOMIC_RELAXED, __HIP_MEMORY_SCOPE_AGENT)
                               : 0x7fffffff;
      if(__all(v >= thresh)) break;
      __builtin_amdgcn_s_sleep(8);
    }
  }
  asm volatile("" ::: "memory");
  __syncthreads();
}
DEVI void signal(int* flag, int val){
  __syncthreads();   // all waves' stores drained before thread 0's release
  if(threadIdx.x==0) __hip_atomic_store(flag, val, __ATOMIC_RELEASE, __HIP_MEMORY_SCOPE_AGENT);
}
// long-wait: single flag, single lane, heavy backoff
DEVI void waitdone(int* f, int thresh){
  __syncthreads();
  if(threadIdx.x==0){
    int spins=0;
    while(__hip_atomic_load(f, __ATOMIC_RELAXED, __HIP_MEMORY_SCOPE_AGENT) < thresh){
      if(spins<8) __builtin_amdgcn_s_sleep(4);
      else        __builtin_amdgcn_s_sleep(64);
      spins++;
    }
  }
  asm volatile("" ::: "memory");
  __syncthreads();
}

// ---------- sort: stable descending by length ----------
__global__ void k_sort(const int* __restrict__ lens, int* __restrict__ order, int* __restrict__ Bt){
  __shared__ int L[BB];
  int i = threadIdx.x;
  L[i] = lens[i];
  __syncthreads();
  int li = L[i]; int rank = 0;
  for(int j=0;j<BB;j++){ int lj=L[j]; rank += (lj>li) || (lj==li && j<i); }
  order[rank] = i;
  if(i<TT){ int c=0; for(int j=0;j<BB;j++) c += (L[j]>i); Bt[i]=c; }
}

// ---------- weight f32 -> bf16 conversion ----------
struct WC13 { const float* src[13]; unsigned short* dst[13]; int n[13]; };
__global__ void k_wconv(WC13 wc){
  int stride = gridDim.x*blockDim.x;
  int tid0 = blockIdx.x*blockDim.x + threadIdx.x;
  for(int s=0;s<13;s++){
    const float4* src=(const float4*)wc.src[s];
    int n4 = wc.n[s]>>2;
    ushort4* dst=(ushort4*)wc.dst[s];
    for(int i=tid0;i<n4;i+=stride){
      float4 v=src[i];
      ushort4 o; o.x=f2bf(v.x); o.y=f2bf(v.y); o.z=f2bf(v.z); o.w=f2bf(v.w);
      dst[i]=o;
    }
  }
}

// ---------- xt build ----------
__global__ void k_xt(const int* __restrict__ caps, const int* __restrict__ order,
                     const float* __restrict__ embW, const unsigned short* __restrict__ gimg,
                     unsigned short* __restrict__ xt){
  int total=BB*TT*1024;
  for(int idx=blockIdx.x*blockDim.x+threadIdx.x; idx<total; idx+=gridDim.x*blockDim.x){
    int k=idx&1023; int bt=idx>>10; int t=bt%TT; int b=bt/TT;
    unsigned short v;
    if(k<512){ int tok=caps[order[b]*TT+t]; v=f2bf(embW[(size_t)tok*512+k]); }
    else v=gimg[b*512+(k-512)];
    xt[idx]=v;
  }
}

// ---------- GEMM, f32 A row-reordered -> bf16, 256-col tiles ----------
__global__ __launch_bounds__(256) void k_gemm_f32A2(
    const float* __restrict__ A, int lda, int rpb, const int* __restrict__ order,
    const unsigned short* __restrict__ W, const float* __restrict__ bias,
    unsigned short* __restrict__ out, int K)
{
  __shared__ unsigned short As[128][136];
  int tid=threadIdx.x, wave=tid>>6, lane=tid&63, l15=lane&15, l4=lane>>4;
  int mb = blockIdx.y*128;
  f32x4 acc[8][4];
  f32x4 z = {0.f,0.f,0.f,0.f};
  #pragma unroll
  for(int i=0;i<8;i++)
    #pragma unroll
    for(int j=0;j<4;j++) acc[i][j]=z;
  int cch=tid&15, r0=tid>>4;
  int nb = blockIdx.x*256 + wave*64;
  for(int kc=0;kc<K;kc+=128){
    __syncthreads();
    #pragma unroll
    for(int rp=0;rp<8;rp++){
      int r=r0+rp*16;
      int m=mb+r;
      int sb = order[m/rpb]*rpb + m%rpb;
      const float* p = A + (size_t)sb*lda + kc + cch*8;
      float4 v0=*(const float4*)p, v1=*(const float4*)(p+4);
      unsigned short* d=&As[r][cch*8];
      d[0]=f2bf(v0.x); d[1]=f2bf(v0.y); d[2]=f2bf(v0.z); d[3]=f2bf(v0.w);
      d[4]=f2bf(v1.x); d[5]=f2bf(v1.y); d[6]=f2bf(v1.z); d[7]=f2bf(v1.w);
    }
    __syncthreads();
    #pragma unroll
    for(int kk=0;kk<4;kk++){
      bf16x8 bfr[4];
      #pragma unroll
      for(int nt=0;nt<4;nt++)
        bfr[nt] = *(const bf16x8*)(W + (size_t)(nb+nt*16+l15)*K + kc + kk*32 + l4*8);
      #pragma unroll
      for(int mt=0;mt<8;mt++){
        bf16x8 af = *(const bf16x8*)&As[mt*16+l15][kk*32+l4*8];
        #pragma unroll
        for(int nt=0;nt<4;nt++) acc[mt][nt]=mfma16(af,bfr[nt],acc[mt][nt]);
      }
    }
  }
  #pragma unroll
  for(int nt=0;nt<4;nt++){
    int n = nb + nt*16 + l15;
    float bs = bias[n];
    #pragma unroll
    for(int mt=0;mt<8;mt++){
      #pragma unroll
      for(int j=0;j<4;j++){
        int row = mb + mt*16 + l4*4 + j;
        float v = acc[mt][nt][j]+bs; v = v>0.f ? v : 0.f;
        out[(size_t)row*512 + n] = f2bf(v);
      }
    }
  }
}

// ---------- device GEMM: bf16 A (ld 512), bf16 W (512x512); BYP=1 -> A via bypass loads ----------
template<int BYP>
DEVI void dev_gemm512(unsigned short (*As)[136], const unsigned short* A, const unsigned short* W,
                      const float* bias, unsigned short* out, int act, int xtile, int mb){
  int tid=threadIdx.x, wave=tid>>6, lane=tid&63, l15=lane&15, l4=lane>>4;
  f32x4 acc[8];
  f32x4 z = {0.f,0.f,0.f,0.f};
  #pragma unroll
  for(int i=0;i<8;i++) acc[i]=z;
  int cch=tid&15, r0=tid>>4;
  int nrow = xtile*64 + wave*16 + l15;
  for(int kc=0;kc<512;kc+=128){
    __syncthreads();
    #pragma unroll
    for(int rp=0;rp<8;rp++){
      int r=r0+rp*16;
      const unsigned short* src = A + (size_t)(mb+r)*512 + kc + cch*8;
      if(BYP) *(uint4*)&As[r][cch*8] = byp16(src);
      else    *(uint4*)&As[r][cch*8] = *(const uint4*)src;
    }
    __syncthreads();
    #pragma unroll
    for(int kk=0;kk<4;kk++){
      bf16x8 bfr = *(const bf16x8*)(W + (size_t)nrow*512 + kc + kk*32 + l4*8);
      #pragma unroll
      for(int mt=0;mt<8;mt++){
        bf16x8 af = *(const bf16x8*)&As[mt*16+l15][kk*32+l4*8];
        acc[mt]=mfma16(af,bfr,acc[mt]);
      }
    }
  }
  float bs = bias ? bias[nrow] : 0.f;
  #pragma unroll
  for(int mt=0;mt<8;mt++){
    #pragma unroll
    for(int j=0;j<4;j++){
      int row = mb + mt*16 + l4*4 + j;
      float v = acc[mt][j]+bs;
      if(act==1) v = fmaxf(v,0.f);
      else if(act==2) v = tanhf(v);
      out[(size_t)row*512+nrow]=f2bf(v);
    }
  }
  __syncthreads();
}

// precompute wrapper (vattn / SC)
struct PreD { const unsigned short* A; const unsigned short* W; const float* bias; unsigned short* out; };
struct PreD2 { PreD d[2]; };
__global__ __launch_bounds__(256) void k_pre(PreD2 dd){
  __shared__ unsigned short As[128][136];
  PreD g = dd.d[blockIdx.z];
  dev_gemm512<0>(As, g.A, g.W, g.bias, g.out, 0, blockIdx.x, blockIdx.y*128);
}

// ---------- persistent-kernel context ----------
struct PCtx {
  const unsigned short *xt, *w_ih, *w_hh, *w_xg, *w_hg;
  const unsigned short *w_saff, *w_satt, *w_haff, *w_hatt, *w_ctx, *w_fc;
  const unsigned short *vattn, *SC;
  const float *bih,*bhh,*bxg,*bhg, *sab,*stbias,*hab,*htb, *alW,*alb, *cxb, *fcb;
  const int *Bt;
  unsigned short *h_hist;   // (TT+1) slots of 128x512 bf16; slot 0 zeroed
  unsigned short *stb;      // TT slots
  unsigned short *tbuf;     // 7 teams x 7 bufs x SLOT
  float *dout;
  int *Lflag;               // [32]
  int *Ldone;               // single counter (own cacheline)
  int *Tflag;               // [7*32]
};

// ---------- device LSTM tile (16 j-cols, 5 strips), c in registers ----------
DEVI void dev_lstm(unsigned short (*As)[136], const PCtx& p, int t, int jblk,
                   const unsigned short* hprev, unsigned short* hout, float creg[2][4]){
  int tid=threadIdx.x, wave=tid>>6, lane=tid&63, l15=lane&15, l4=lane>>4;
  int jb = jblk*16;
  f32x4 acc[2][5];
  f32x4 z = {0.f,0.f,0.f,0.f};
  #pragma unroll
  for(int m=0;m<2;m++)
    #pragma unroll
    for(int s=0;s<5;s++) acc[m][s]=z;
  int cch=tid&15, r0=tid>>4;
  for(int kc=0;kc<1536;kc+=128){
    __syncthreads();
    #pragma unroll
    for(int rp=0;rp<8;rp++){
      int r=r0+rp*16;
      int kg = kc + cch*8;
      if(kg<1024){
        *(uint4*)&As[r][cch*8] = *(const uint4*)(p.xt + (size_t)r*(TT*1024) + t*1024 + kg);
      } else {
        *(uint4*)&As[r][cch*8] = byp16(hprev + (size_t)r*512 + (kg-1024));   // cross-block h
      }
    }
    __syncthreads();
    #pragma unroll
    for(int kk=0;kk<4;kk++){
      int kg = kc + kk*32 + l4*8;
      bf16x8 bfr[5];
      #pragma unroll
      for(int s=0;s<5;s++){
        int row = (s<4) ? (s*512 + jb + l15) : (jb + l15);
        const unsigned short* wp;
        if(s<4) wp = (kg<1024) ? (p.w_ih + (size_t)row*1024 + kg) : (p.w_hh + (size_t)row*512 + (kg-1024));
        else    wp = (kg<1024) ? (p.w_xg + (size_t)row*1024 + kg) : (p.w_hg + (size_t)row*512 + (kg-1024));
        bfr[s] = *(const bf16x8*)wp;
      }
      #pragma unroll
      for(int m=0;m<2;m++){
        int mt = wave*2+m;
        bf16x8 af = *(const bf16x8*)&As[mt*16+l15][kk*32+l4*8];
        #pragma unroll
        for(int s=0;s<5;s++) acc[m][s]=mfma16(af,bfr[s],acc[m][s]);
      }
    }
  }
  int bt = p.Bt[t];
  int j = jb + l15;
  float bi  = p.bih[j]      + p.bhh[j];
  float bff = p.bih[512+j]  + p.bhh[512+j];
  float bg  = p.bih[1024+j] + p.bhh[1024+j];
  float bo  = p.bih[1536+j] + p.bhh[1536+j];
  float bs  = p.bxg[j] + p.bhg[j];
  unsigned short* stt = p.stb + (size_t)t*SLOT;
  #pragma unroll
  for(int m=0;m<2;m++){
    int mt = wave*2+m;
    #pragma unroll
    for(int jj=0;jj<4;jj++){
      int b = mt*16 + l4*4 + jj;
      float iv = sigm(acc[m][0][jj]+bi);
      float fv = sigm(acc[m][1][jj]+bff);
      float gv = tanhf(acc[m][2][jj]+bg);
      float ov = sigm(acc[m][3][jj]+bo);
      float sv = sigm(acc[m][4][jj]+bs);
      float cn = fv*creg[m][jj] + iv*gv;
      float tc = tanhf(cn);
      size_t idx=(size_t)b*512+j;
      if(b<bt){ hout[idx]=f2bf(ov*tc); creg[m][jj]=cn; }
      else {
        unsigned pr = byp4(hprev + (idx & ~(size_t)1));
        hout[idx] = (j&1) ? (unsigned short)(pr>>16) : (unsigned short)pr;
      }
      stt[idx]=f2bf(sv*tc);
    }
  }
}

// ---------- device attention for one batch row (ha/sa staged in LDS) ----------
DEVI void dev_attn(float* sS, float* sA, unsigned short* sHA, unsigned short* sSA,
                   int b, const PCtx& p,
                   const unsigned short* satt, const unsigned short* hatt,
                   const unsigned short* scs, const unsigned short* sch,
                   unsigned short* outl){
  int tid=threadIdx.x;
  if(tid<64)       *(uint4*)&sHA[tid*8] = byp16(hatt + (size_t)b*512 + tid*8);
  else if(tid<128){ int q=tid-64; *(uint4*)&sSA[q*8] = byp16(satt + (size_t)b*512 + q*8); }
  __syncthreads();
  int gid=tid>>4, gl=tid&15;
  #pragma unroll
  for(int rp=0;rp<4;rp++){
    int pp = rp*16 + gid;
    float s = 0.f;
    if(pp<50){
      if(pp<NPIX){
        const unsigned short* vp = p.vattn + ((size_t)b*NPIX + pp)*512;  // cached
        for(int k=gl*32;k<gl*32+32;k++) s += tanhf(bf2f(vp[k]) + bf2f(sHA[k])) * p.alW[k];
      } else {
        for(int k=gl*32;k<gl*32+32;k++) s += tanhf(bf2f(sSA[k]) + bf2f(sHA[k])) * p.alW[k];
      }
    }
    #pragma unroll
    for(int off=8;off>=1;off>>=1) s += __shfl_xor(s, off);
    if(gl==0 && pp<50) sS[pp] = s + p.alb[0];
  }
  __syncthreads();
  if(tid<64){
    float sv = (tid<50) ? sS[tid] : -1e30f;
    float m = sv;
    #pragma unroll
    for(int off=32;off>=1;off>>=1) m = fmaxf(m, __shfl_xor(m, off));
    float e = (tid<50) ? expf(sv-m) : 0.f;
    float sum = e;
    #pragma unroll
    for(int off=32;off>=1;off>>=1) sum += __shfl_xor(sum, off);
    if(tid<50) sA[tid] = e/sum;
  }
  __syncthreads();
  float a49 = sA[49];
  {
    int n0 = tid*2;
    unsigned schU = byp4(sch + (size_t)b*512 + n0);
    unsigned scsU = byp4(scs + (size_t)b*512 + n0);
    float c0 = bf2f((unsigned short)schU), c1 = bf2f((unsigned short)(schU>>16));
    float s0 = bf2f((unsigned short)scsU), s1 = bf2f((unsigned short)(scsU>>16));
    float acc0 = c0 + a49*s0 + p.cxb[n0];
    float acc1 = c1 + a49*s1 + p.cxb[n0+1];
    const unsigned short* sp = p.SC + (size_t)b*NPIX*512 + n0;   // cached
    for(int pp=0;pp<NPIX;pp++){
      unsigned u = *(const unsigned*)(sp + (size_t)pp*512);
      acc0 += sA[pp]*bf2f((unsigned short)u);
      acc1 += sA[pp]*bf2f((unsigned short)(u>>16));
    }
    unsigned o = ((unsigned)f2bf(tanhf(acc1))<<16) | (unsigned)f2bf(tanhf(acc0));
    *(unsigned*)(outl + (size_t)b*512 + n0) = o;
  }
  __syncthreads();
}

// ---------- fc: stage outl ONCE into big LDS, run all vocab tiles from it ----------
DEVI void dev_fc_all(unsigned short (*As2)[520], const PCtx& p, int t, int w,
                     const unsigned short* outl){
  int tid=threadIdx.x;
  __syncthreads();
  #pragma unroll
  for(int i=0;i<32;i++){
    int idx = i*256 + tid;          // 8192 groups of 8 elems
    int r = idx>>6, c = (idx&63)<<3;
    *(uint4*)&As2[r][c] = byp16(outl + (size_t)r*512 + c);
  }
  __syncthreads();
  int wave=tid>>6, lane=tid&63, l15=lane&15, l4=lane>>4;
  int bt = p.Bt[t];
  for(int x=w; x<157; x+=32){
    f32x4 acc[8];
    f32x4 z = {0.f,0.f,0.f,0.f};
    #pragma unroll
    for(int i=0;i<8;i++) acc[i]=z;
    int nbase = x*64 + wave*16;
    int nr = nbase + l15; if(nr > VOCAB-1) nr = VOCAB-1;
    #pragma unroll 4
    for(int kk=0;kk<16;kk++){
      bf16x8 bfr = *(const bf16x8*)(p.w_fc + (size_t)nr*512 + kk*32 + l4*8);
      #pragma unroll
      for(int mt=0;mt<8;mt++){
        if(mt*16 < bt){
          bf16x8 af = *(const bf16x8*)&As2[mt*16+l15][kk*32+l4*8];
          acc[mt]=mfma16(af,bfr,acc[mt]);
        }
      }
    }
    int n = nbase + l15; bool nok = n < VOCAB;
    float bs = nok ? p.fcb[n] : 0.f;
    #pragma unroll
    for(int mt=0;mt<8;mt++){
      #pragma unroll
      for(int j=0;j<4;j++){
        int b = mt*16 + l4*4 + j;
        float v = (b<bt) ? (acc[mt][j]+bs) : 0.f;
        if(nok) p.dout[(size_t)b*(TT*VOCAB) + (size_t)t*VOCAB + n] = v;
      }
    }
  }
  __syncthreads();
}

// ---------- the persistent kernel: L-group (0-31) + 7 teams of 32 ----------
__global__ __launch_bounds__(256) void k_persist(PCtx p){
  __shared__ __align__(16) char smem[133760];
  auto As  = (unsigned short (*)[136])smem;
  auto As2 = (unsigned short (*)[520])smem;
  float* sS = (float*)(smem + 133120);
  float* sA = sS + 52;
  unsigned short* sHA = (unsigned short*)smem;        // attn-phase staging (1KB)
  unsigned short* sSA = sHA + 512;
  int cb = blockIdx.x;
  if(cb < 32){
    float creg[2][4];
    #pragma unroll
    for(int m=0;m<2;m++)
      #pragma unroll
      for(int j=0;j<4;j++) creg[m][j]=0.f;
    for(int t=0;t<TT;t++){
      if(t>0){
        waitflags(p.Lflag, t);
        if(cb==0 && threadIdx.x==0)
          __hip_atomic_store(p.Ldone, t, __ATOMIC_RELEASE, __HIP_MEMORY_SCOPE_AGENT);
      }
      dev_lstm(As, p, t, cb, p.h_hist + (size_t)t*SLOT, p.h_hist + (size_t)(t+1)*SLOT, creg);
      signal(&p.Lflag[cb], t+1);
    }
    if(cb==0){
      waitflags(p.Lflag, TT);
      if(threadIdx.x==0)
        __hip_atomic_store(p.Ldone, TT, __ATOMIC_RELEASE, __HIP_MEMORY_SCOPE_AGENT);
    }
  } else {
    int team = (cb-32)>>5, w = (cb-32)&31;
    unsigned short* S = p.tbuf + (size_t)team*7*SLOT;
    unsigned short *Saff=S, *Haff=S+SLOT, *Outl=S+2*SLOT, *Satt=S+3*SLOT,
                   *Hatt=S+4*SLOT, *Scs=S+5*SLOT, *Sch=S+6*SLOT;
    int* tf = p.Tflag + team*32;
    int it=0;
    for(int t=team; t<TT; t+=7, it++){
      waitdone(p.Ldone, t+1);
      // A: aff
      if(w<8)       dev_gemm512<1>(As, p.stb + (size_t)t*SLOT,        p.w_saff, p.sab, Saff, 1, w,   0);
      else if(w<16) dev_gemm512<1>(As, p.h_hist + (size_t)(t+1)*SLOT, p.w_haff, p.hab, Haff, 2, w-8, 0);
      signal(&tf[w], it*3+1); waitflags(tf, it*3+1);
      // B: att projections
      if(w<8)       dev_gemm512<1>(As, Saff, p.w_satt, p.stbias, Satt, 0, w,    0);
      else if(w<16) dev_gemm512<1>(As, Haff, p.w_hatt, p.htb,    Hatt, 0, w-8,  0);
      else if(w<24) dev_gemm512<1>(As, Saff, p.w_ctx,  nullptr,  Scs,  0, w-16, 0);
      else          dev_gemm512<1>(As, Haff, p.w_ctx,  nullptr,  Sch,  0, w-24, 0);
      signal(&tf[w], it*3+2); waitflags(tf, it*3+2);
      // C: attention (4 rows per block)
      for(int r=0;r<4;r++) dev_attn(sS, sA, sHA, sSA, w*4+r, p, Satt, Hatt, Scs, Sch, Outl);
      signal(&tf[w], it*3+3); waitflags(tf, it*3+3);
      // D: fc (staged once, ~5 tiles per block)
      dev_fc_all(As2, p, t, w, Outl);
    }
  }
}

// ---------- host launch ----------
extern "C" void kernel_launch(void* const* d_in, const int* in_sizes, int n_in,
                              void* d_out, int out_size, void* d_ws, size_t ws_size,
                              hipStream_t stream)
{
  const float* enc  =(const float*)d_in[0];
  const float* gfeat=(const float*)d_in[1];
  const int*   caps =(const int*)d_in[2];
  const int*   lens =(const int*)d_in[3];
  const float* embW =(const float*)d_in[4];
  const float* e2hW =(const float*)d_in[5];  const float* e2hb=(const float*)d_in[6];
  const float* gfW  =(const float*)d_in[7];  const float* gfb =(const float*)d_in[8];
  const float* fcW  =(const float*)d_in[9];  const float* fcb =(const float*)d_in[10];
  const float* WihF =(const float*)d_in[11]; const float* bih =(const float*)d_in[12];
  const float* WhhF =(const float*)d_in[13]; const float* bhh =(const float*)d_in[14];
  const float* xgWF =(const float*)d_in[15]; const float* bxg =(const float*)d_in[16];
  const float* hgWF =(const float*)d_in[17]; const float* bhg =(const float*)d_in[18];
  const float* saWF =(const float*)d_in[19]; const float* sab =(const float*)d_in[20];
  const float* stWF =(const float*)d_in[21]; const float* stbias=(const float*)d_in[22];
  const float* haWF =(const float*)d_in[23]; const float* hab =(const float*)d_in[24];
  const float* htWF =(const float*)d_in[25]; const float* htb =(const float*)d_in[26];
  const float* vaWF =(const float*)d_in[27]; const float* vab =(const float*)d_in[28];
  const float* alW  =(const float*)d_in[29]; const float* alb =(const float*)d_in[30];
  const float* cxWF =(const float*)d_in[31]; const float* cxb =(const float*)d_in[32];

  char* base=(char*)d_ws; size_t off=0;
  auto alloc=[&](size_t bytes)->void*{ void* r=base+off; off += (bytes+255)&~(size_t)255; return r; };

  int* order=(int*)alloc(BB*4);
  int* Bt   =(int*)alloc(32*4);
  unsigned short* w_e2h =(unsigned short*)alloc((size_t)512*2048*2);   // aliased by stb_hist in persist
  unsigned short* w_gf  =(unsigned short*)alloc((size_t)512*2048*2);   // (contiguous with w_e2h)
  unsigned short* w_fc  =(unsigned short*)alloc((size_t)VOCAB*512*2);
  unsigned short* w_ih  =(unsigned short*)alloc((size_t)2048*1024*2);
  unsigned short* w_hh  =(unsigned short*)alloc((size_t)2048*512*2);
  unsigned short* w_xg  =(unsigned short*)alloc((size_t)512*1024*2);
  unsigned short* w_hg  =(unsigned short*)alloc((size_t)512*512*2);
  unsigned short* w_saff=(unsigned short*)alloc((size_t)512*512*2);
  unsigned short* w_satt=(unsigned short*)alloc((size_t)512*512*2);
  unsigned short* w_haff=(unsigned short*)alloc((size_t)512*512*2);
  unsigned short* w_hatt=(unsigned short*)alloc((size_t)512*512*2);
  unsigned short* w_vatt=(unsigned short*)alloc((size_t)512*512*2);
  unsigned short* w_ctx =(unsigned short*)alloc((size_t)512*512*2);
  unsigned short* spatial=(unsigned short*)alloc((size_t)BB*NPIX*512*2); // aliased by h_hist in persist
  unsigned short* vattn  =(unsigned short*)alloc((size_t)BB*NPIX*512*2);
  unsigned short* SC     =(unsigned short*)alloc((size_t)BB*NPIX*512*2);
  unsigned short* gimg   =(unsigned short*)alloc((size_t)BB*512*2);
  unsigned short* xt     =(unsigned short*)alloc((size_t)BB*TT*1024*2);
  int* flags =(int*)alloc(4096);                 // Lflag[32]@0, Ldone@32, Tflag@64
  unsigned short* tbuf=(unsigned short*)alloc((size_t)7*7*SLOT*2);

  unsigned short* stb_hist = w_e2h;              // 30*SLOT*2 = 3.93MB <= 4MB (w_e2h+w_gf)
  unsigned short* h_hist   = spatial;            // 31*SLOT*2 = 4.06MB <= 6.42MB

  k_sort<<<1,BB,0,stream>>>(lens, order, Bt);

  WC13 wc;
  const float* srcs[13] = {e2hW,gfW,fcW,WihF,WhhF,xgWF,hgWF,saWF,stWF,haWF,htWF,vaWF,cxWF};
  unsigned short* dsts[13] = {w_e2h,w_gf,w_fc,w_ih,w_hh,w_xg,w_hg,w_saff,w_satt,w_haff,w_hatt,w_vatt,w_ctx};
  int ns[13] = {512*2048,512*2048,VOCAB*512,2048*1024,2048*512,512*1024,512*512,512*512,512*512,512*512,512*512,512*512,512*512};
  for(int i=0;i<13;i++){ wc.src[i]=srcs[i]; wc.dst[i]=dsts[i]; wc.n[i]=ns[i]; }
  k_wconv<<<1024,256,0,stream>>>(wc);

  // spatial / gimg / xt / vattn / SC precompute
  k_gemm_f32A2<<<dim3(2,NPIX),256,0,stream>>>(enc, ENCD, NPIX, order, w_e2h, e2hb, spatial, ENCD);
  k_gemm_f32A2<<<dim3(2,1),  256,0,stream>>>(gfeat, ENCD, 1, order, w_gf, gfb, gimg, ENCD);
  k_xt<<<1024,256,0,stream>>>(caps, order, embW, gimg, xt);
  {
    PreD2 dv{};
    dv.d[0] = PreD{spatial, w_vatt, vab,     vattn};
    dv.d[1] = PreD{spatial, w_ctx,  nullptr, SC};
    k_pre<<<dim3(8,NPIX,2),256,0,stream>>>(dv);
  }

  // zero h slot 0 and flags (stream-ordered after precompute reads of spatial/w_e2h)
  hipMemsetAsync(h_hist, 0, (size_t)SLOT*2, stream);
  hipMemsetAsync(flags, 0, 4096, stream);

  PCtx pc;
  pc.xt=xt; pc.w_ih=w_ih; pc.w_hh=w_hh; pc.w_xg=w_xg; pc.w_hg=w_hg;
  pc.w_saff=w_saff; pc.w_satt=w_satt; pc.w_haff=w_haff; pc.w_hatt=w_hatt; pc.w_ctx=w_ctx; pc.w_fc=w_fc;
  pc.vattn=vattn; pc.SC=SC;
  pc.bih=bih; pc.bhh=bhh; pc.bxg=bxg; pc.bhg=bhg;
  pc.sab=sab; pc.stbias=stbias; pc.hab=hab; pc.htb=htb;
  pc.alW=alW; pc.alb=alb; pc.cxb=cxb; pc.fcb=fcb;
  pc.Bt=Bt;
  pc.h_hist=h_hist; pc.stb=stb_hist; pc.tbuf=tbuf;
  pc.dout=(float*)d_out;
  pc.Lflag=flags; pc.Ldone=flags+32; pc.Tflag=flags+64;

  k_persist<<<256,256,0,stream>>>(pc);
}